// Round 4
// baseline (361.149 us; speedup 1.0000x reference)
//
#include <hip/hip_runtime.h>
#include <stdint.h>

#define HEADS 3
#define HID 128
#define FDIM (HEADS * HID)   // 384

typedef __attribute__((ext_vector_type(8))) short bf16x8;
typedef __attribute__((ext_vector_type(4))) float f32x4;

__device__ __forceinline__ float lrelu(float x) { return x >= 0.f ? x : 0.2f * x; }
__device__ __forceinline__ float rrelu(float x) {
    const float SLOPE = (1.0f / 8.0f + 1.0f / 3.0f) * 0.5f;
    return x >= 0.f ? x : SLOPE * x;
}
__device__ __forceinline__ unsigned short f2bf(float f) {
    union { float f; unsigned u; } c; c.f = f;
    unsigned r = c.u + 0x7FFF + ((c.u >> 16) & 1);   // RNE
    return (unsigned short)(r >> 16);
}
__device__ __forceinline__ float bf2f(unsigned short b) {
    union { unsigned u; float f; } c; c.u = (unsigned)b << 16;
    return c.f;
}

__device__ __forceinline__ void gload_lds16(const void* g, void* l) {
    __builtin_amdgcn_global_load_lds(
        (const __attribute__((address_space(1))) void*)g,
        (__attribute__((address_space(3))) void*)l, 16, 0, 0);
}

// ---------------- CSR build (counting sort by dst) ----------------

__global__ void k_hist(const int* __restrict__ dst, int E, int* __restrict__ cnt) {
    for (int i = blockIdx.x * blockDim.x + threadIdx.x; i < E; i += gridDim.x * blockDim.x)
        atomicAdd(&cnt[dst[i]], 1);
}

#define SC_T 256
#define SC_E 8
#define SC_CHUNK (SC_T * SC_E)   // 2048

__global__ __launch_bounds__(SC_T) void k_scan1(const int* __restrict__ cnt,
                                                int* __restrict__ exc,
                                                int* __restrict__ bsum, int n) {
    __shared__ int sm[SC_T];
    int b = blockIdx.x, t = threadIdx.x;
    int base = b * SC_CHUNK + t * SC_E;
    int v[SC_E];
    int s = 0;
#pragma unroll
    for (int i = 0; i < SC_E; i++) {
        int idx = base + i;
        v[i] = (idx < n) ? cnt[idx] : 0;
        s += v[i];
    }
    sm[t] = s;
    __syncthreads();
    for (int off = 1; off < SC_T; off <<= 1) {
        int x = (t >= off) ? sm[t - off] : 0;
        __syncthreads();
        sm[t] += x;
        __syncthreads();
    }
    int run = sm[t] - s;
    if (t == SC_T - 1) bsum[b] = sm[t];
#pragma unroll
    for (int i = 0; i < SC_E; i++) {
        int idx = base + i;
        if (idx < n) exc[idx] = run;
        run += v[i];
    }
}

__global__ __launch_bounds__(256) void k_scan2(const int* __restrict__ bsum,
                                               int* __restrict__ bpre, int nb) {
    __shared__ int sm[256];
    int t = threadIdx.x;
    int v = (t < nb) ? bsum[t] : 0;
    sm[t] = v;
    __syncthreads();
    for (int off = 1; off < 256; off <<= 1) {
        int x = (t >= off) ? sm[t - off] : 0;
        __syncthreads();
        sm[t] += x;
        __syncthreads();
    }
    if (t < nb) bpre[t + 1] = sm[t];
    if (t == 0) bpre[0] = 0;
}

__global__ void k_scan3(int* __restrict__ offs, const int* __restrict__ bpre,
                        int* __restrict__ cursor, int n, int nb) {
    int i = blockIdx.x * blockDim.x + threadIdx.x;
    if (i < n) {
        int o = offs[i] + bpre[i / SC_CHUNK];
        offs[i] = o;
        cursor[i] = o;
    }
    if (i == 0) offs[n] = bpre[nb];
}

__global__ void k_scatter(const int* __restrict__ src, const int* __restrict__ dst, int E,
                          int* __restrict__ cursor, int* __restrict__ ssrc,
                          int* __restrict__ sdst) {
    for (int i = blockIdx.x * blockDim.x + threadIdx.x; i < E; i += gridDim.x * blockDim.x) {
        int d = dst[i];
        int p = atomicAdd(&cursor[d], 1);
        ssrc[p] = src[i];
        sdst[p] = d;
    }
}

// ---------------- bf16 converts ----------------

__global__ void k_cvt_concat(const float* __restrict__ z, const float* __restrict__ x,
                             unsigned short* __restrict__ A, int Nn, int Mpad) {
    int total = Mpad * 64;
    for (int i = blockIdx.x * blockDim.x + threadIdx.x; i < total;
         i += gridDim.x * blockDim.x) {
        int row = i >> 6;
        int c4 = (i & 63) * 4;
        float4 v = make_float4(0.f, 0.f, 0.f, 0.f);
        if (row < Nn) {
            const float* sp = (c4 < 128) ? (z + (size_t)row * 128 + c4)
                                         : (x + (size_t)row * 128 + (c4 - 128));
            v = *(const float4*)sp;
        }
        unsigned short o[4] = {f2bf(v.x), f2bf(v.y), f2bf(v.z), f2bf(v.w)};
        *(uint2*)&A[(size_t)row * 256 + c4] = *(uint2*)o;
    }
}

__global__ void k_cvt_wt(const float* __restrict__ W, unsigned short* __restrict__ WT,
                         int K, int Ncols) {
    int n = blockIdx.x;
    for (int k = threadIdx.x; k < K; k += blockDim.x)
        WT[(size_t)n * K + k] = f2bf(W[(size_t)k * Ncols + n]);
}

// ---------------- bf16 MFMA GEMM ----------------

__global__ __launch_bounds__(256) void k_gemm_bf16(
    const unsigned short* __restrict__ A,
    const unsigned short* __restrict__ BT,
    unsigned short* __restrict__ C,
    int K, int Ncols) {
    __shared__ __align__(16) unsigned short As[128 * 32];
    __shared__ __align__(16) unsigned short Bs[128 * 32];
    int tid = threadIdx.x;
    int w = tid >> 6, lane = tid & 63;
    int row0 = blockIdx.x * 128;
    int col0 = blockIdx.y * 128;
    int wr = w >> 1, wc = w & 1;

    f32x4 acc[4][4] = {};
    int frow = lane & 15;
    int fk = (lane >> 4) * 8;

    for (int k0 = 0; k0 < K; k0 += 32) {
#pragma unroll
        for (int i = 0; i < 2; i++) {
            int c = (i * 4 + w) * 64 + lane;
            gload_lds16(A + (size_t)(row0 + (c >> 2)) * K + k0 + (c & 3) * 8,
                        (char*)As + (i * 4 + w) * 1024);
        }
#pragma unroll
        for (int i = 0; i < 2; i++) {
            int c = (i * 4 + w) * 64 + lane;
            gload_lds16(BT + (size_t)(col0 + (c >> 2)) * K + k0 + (c & 3) * 8,
                        (char*)Bs + (i * 4 + w) * 1024);
        }
        asm volatile("s_waitcnt vmcnt(0)" ::: "memory");
        __syncthreads();

        bf16x8 af[4], bfr[4];
#pragma unroll
        for (int m = 0; m < 4; m++)
            af[m] = *(const bf16x8*)&As[(wr * 64 + m * 16 + frow) * 32 + fk];
#pragma unroll
        for (int n = 0; n < 4; n++)
            bfr[n] = *(const bf16x8*)&Bs[(wc * 64 + n * 16 + frow) * 32 + fk];
#pragma unroll
        for (int m = 0; m < 4; m++)
#pragma unroll
            for (int n = 0; n < 4; n++)
                acc[m][n] = __builtin_amdgcn_mfma_f32_16x16x32_bf16(af[m], bfr[n], acc[m][n], 0, 0, 0);
        __syncthreads();
    }

    int ccol = lane & 15, crow = (lane >> 4) * 4;
#pragma unroll
    for (int m = 0; m < 4; m++)
#pragma unroll
        for (int n = 0; n < 4; n++)
#pragma unroll
            for (int j = 0; j < 4; j++) {
                int r = row0 + wr * 64 + m * 16 + crow + j;
                int cc = col0 + wc * 64 + n * 16 + ccol;
                C[(size_t)r * Ncols + cc] = f2bf(acc[m][n][j]);
            }
}

// ---------------- per-node attention logits ----------------

__global__ __launch_bounds__(128) void k_edge_logits(const unsigned short* __restrict__ H,
                                                     const float* __restrict__ asrc,
                                                     const float* __restrict__ adst,
                                                     float* __restrict__ es,
                                                     float* __restrict__ ed, int Nn) {
    int n = blockIdx.x;
    int t = threadIdx.x;
    int lane = t & 63, wv = t >> 6;
    __shared__ float red[2][HEADS][2];
#pragma unroll
    for (int h = 0; h < HEADS; h++) {
        float v = bf2f(H[(size_t)n * FDIM + h * HID + t]);
        float ps = v * asrc[h * HID + t];
        float pd = v * adst[h * HID + t];
#pragma unroll
        for (int off = 32; off > 0; off >>= 1) {
            ps += __shfl_down(ps, off);
            pd += __shfl_down(pd, off);
        }
        if (lane == 0) { red[wv][h][0] = ps; red[wv][h][1] = pd; }
    }
    __syncthreads();
    if (t < HEADS) {
        es[n * HEADS + t] = red[0][t][0] + red[1][t][0];
        ed[n * HEADS + t] = red[0][t][1] + red[1][t][1];
    }
}

// ---------------- per-edge weights (one thread per CSR slot) ----------------

__global__ void k_edge_w(const int* __restrict__ ssrc, const int* __restrict__ sdst,
                         const float* __restrict__ es, const float* __restrict__ ed,
                         float4* __restrict__ w4, int E) {
    for (int j = blockIdx.x * blockDim.x + threadIdx.x; j < E; j += gridDim.x * blockDim.x) {
        int s = ssrc[j], d = sdst[j];
        float w0 = __expf(lrelu(es[s * 3 + 0] + ed[d * 3 + 0]));
        float w1 = __expf(lrelu(es[s * 3 + 1] + ed[d * 3 + 1]));
        float w2 = __expf(lrelu(es[s * 3 + 2] + ed[d * 3 + 2]));
        w4[j] = make_float4(w0, w1, w2, 0.f);
    }
}

// per-node: self weight + inverse denominators
__global__ void k_den(const float* __restrict__ es, const float* __restrict__ ed,
                      const int* __restrict__ offs, const float4* __restrict__ w4,
                      float4* __restrict__ wself, float4* __restrict__ invden, int Nn) {
    for (int n = blockIdx.x * blockDim.x + threadIdx.x; n < Nn; n += gridDim.x * blockDim.x) {
        float s0 = __expf(lrelu(es[n * 3 + 0] + ed[n * 3 + 0]));
        float s1 = __expf(lrelu(es[n * 3 + 1] + ed[n * 3 + 1]));
        float s2 = __expf(lrelu(es[n * 3 + 2] + ed[n * 3 + 2]));
        float d0 = s0, d1 = s1, d2 = s2;
        int j0 = offs[n], j1 = offs[n + 1];
        for (int j = j0; j < j1; j++) {
            float4 w = w4[j];
            d0 += w.x; d1 += w.y; d2 += w.z;
        }
        wself[n] = make_float4(s0, s1, s2, 0.f);
        invden[n] = make_float4(1.f / d0, 1.f / d1, 1.f / d2, 0.f);
    }
}

// ---------------- GAT aggregate, layer 1 (mean heads + bias + rrelu) ----------------

__global__ __launch_bounds__(128) void k_gat_mean(const unsigned short* __restrict__ H,
                                                  const float4* __restrict__ w4,
                                                  const float4* __restrict__ wself,
                                                  const float4* __restrict__ invden,
                                                  const int* __restrict__ offs,
                                                  const int* __restrict__ ssrc,
                                                  const float* __restrict__ b,
                                                  unsigned short* __restrict__ out, int Nn) {
    int n = blockIdx.x;
    int c = threadIdx.x;
    float4 ws = wself[n];
    const unsigned short* hp = H + (size_t)n * FDIM + c;
    float acc0 = ws.x * bf2f(hp[0]);
    float acc1 = ws.y * bf2f(hp[HID]);
    float acc2 = ws.z * bf2f(hp[2 * HID]);
    int j0 = offs[n], j1 = offs[n + 1];
    for (int j = j0; j < j1; j++) {
        int s = ssrc[j];
        float4 w = w4[j];
        hp = H + (size_t)s * FDIM + c;
        acc0 = fmaf(w.x, bf2f(hp[0]), acc0);
        acc1 = fmaf(w.y, bf2f(hp[HID]), acc1);
        acc2 = fmaf(w.z, bf2f(hp[2 * HID]), acc2);
    }
    float4 iv = invden[n];
    float m = (acc0 * iv.x + acc1 * iv.y + acc2 * iv.z) * (1.f / 3.f) + b[c];
    out[(size_t)n * HID + c] = f2bf(rrelu(m));
}

// ---------------- GAT aggregate, layer 2 (concat) + linear + sigmoid ----------------

__global__ __launch_bounds__(128) void k_gat_cat_final(const unsigned short* __restrict__ H,
                                                       const float4* __restrict__ w4,
                                                       const float4* __restrict__ wself,
                                                       const float4* __restrict__ invden,
                                                       const int* __restrict__ offs,
                                                       const int* __restrict__ ssrc,
                                                       const float* __restrict__ b,
                                                       const float* __restrict__ Wl,
                                                       const float* __restrict__ bl,
                                                       float* __restrict__ out, int Nn) {
    int n = blockIdx.x;
    int c = threadIdx.x;
    float4 ws = wself[n];
    const unsigned short* hp = H + (size_t)n * FDIM + c;
    float acc0 = ws.x * bf2f(hp[0]);
    float acc1 = ws.y * bf2f(hp[HID]);
    float acc2 = ws.z * bf2f(hp[2 * HID]);
    int j0 = offs[n], j1 = offs[n + 1];
    for (int j = j0; j < j1; j++) {
        int s = ssrc[j];
        float4 w = w4[j];
        hp = H + (size_t)s * FDIM + c;
        acc0 = fmaf(w.x, bf2f(hp[0]), acc0);
        acc1 = fmaf(w.y, bf2f(hp[HID]), acc1);
        acc2 = fmaf(w.z, bf2f(hp[2 * HID]), acc2);
    }
    float4 iv = invden[n];
    float r0 = rrelu(acc0 * iv.x + b[c]);
    float r1 = rrelu(acc1 * iv.y + b[HID + c]);
    float r2 = rrelu(acc2 * iv.z + b[2 * HID + c]);
    float p = r0 * Wl[c] + r1 * Wl[HID + c] + r2 * Wl[2 * HID + c];
    int lane = c & 63, wv = c >> 6;
#pragma unroll
    for (int off = 32; off > 0; off >>= 1) p += __shfl_down(p, off);
    __shared__ float red[2];
    if (lane == 0) red[wv] = p;
    __syncthreads();
    if (c == 0) out[n] = 1.f / (1.f + __expf(-(red[0] + red[1] + bl[0])));
}

// ---------------- launch ----------------

extern "C" void kernel_launch(void* const* d_in, const int* in_sizes, int n_in,
                              void* d_out, int out_size, void* d_ws, size_t ws_size,
                              hipStream_t stream) {
    const float* z   = (const float*)d_in[0];
    const float* x   = (const float*)d_in[1];
    const int*   ei  = (const int*)d_in[2];
    const float* W1  = (const float*)d_in[3];
    const float* a1s = (const float*)d_in[4];
    const float* a1d = (const float*)d_in[5];
    const float* b1  = (const float*)d_in[6];
    const float* W2  = (const float*)d_in[7];
    const float* a2s = (const float*)d_in[8];
    const float* a2d = (const float*)d_in[9];
    const float* b2  = (const float*)d_in[10];
    const float* Wl  = (const float*)d_in[11];
    const float* bl  = (const float*)d_in[12];
    float* outp = (float*)d_out;

    int Nn = in_sizes[0] / 128;
    int E  = in_sizes[2] / 2;
    int Mpad = (Nn + 127) & ~127;
    int nb = (Nn + SC_CHUNK - 1) / SC_CHUNK;

    char* p = (char*)d_ws;
    auto carve = [&](size_t bytes) -> char* {
        char* r = p;
        p += (bytes + 255) & ~(size_t)255;
        return r;
    };
    int*            offs   = (int*)carve((size_t)(Nn + 1) * 4);
    int*            cursor = (int*)carve((size_t)Nn * 4);
    int*            ssrc   = (int*)carve((size_t)E * 4);
    int*            sdst   = (int*)carve((size_t)E * 4);
    int*            bsum   = (int*)carve((size_t)(nb + 1) * 4);
    int*            bpre   = (int*)carve((size_t)(nb + 1) * 4);
    float*          e1s    = (float*)carve((size_t)Nn * 3 * 4);
    float*          e1d    = (float*)carve((size_t)Nn * 3 * 4);
    float4*         w4     = (float4*)carve((size_t)E * 16);
    float4*         wself  = (float4*)carve((size_t)Nn * 16);
    float4*         invden = (float4*)carve((size_t)Nn * 16);
    unsigned short* Abf    = (unsigned short*)carve((size_t)Mpad * 256 * 2);
    unsigned short* W1T    = (unsigned short*)carve((size_t)FDIM * 256 * 2);
    unsigned short* W2T    = (unsigned short*)carve((size_t)FDIM * 128 * 2);
    unsigned short* Hbf    = (unsigned short*)carve((size_t)Mpad * FDIM * 2);
    unsigned short* H2in   = (unsigned short*)carve((size_t)Mpad * 128 * 2);

    const int* srcI = ei;
    const int* dstI = ei + E;

    // CSR build
    hipMemsetAsync(cursor, 0, (size_t)Nn * 4, stream);
    k_hist<<<256, 256, 0, stream>>>(dstI, E, cursor);
    k_scan1<<<nb, SC_T, 0, stream>>>(cursor, offs, bsum, Nn);
    k_scan2<<<1, 256, 0, stream>>>(bsum, bpre, nb);
    k_scan3<<<(Nn + 255) / 256, 256, 0, stream>>>(offs, bpre, cursor, Nn, nb);
    k_scatter<<<256, 256, 0, stream>>>(srcI, dstI, E, cursor, ssrc, sdst);

    // bf16 converts
    k_cvt_concat<<<2048, 256, 0, stream>>>(z, x, Abf, Nn, Mpad);
    k_cvt_wt<<<FDIM, 256, 0, stream>>>(W1, W1T, 256, FDIM);
    k_cvt_wt<<<FDIM, 128, 0, stream>>>(W2, W2T, 128, FDIM);
    hipMemsetAsync(H2in + (size_t)Nn * 128, 0, (size_t)(Mpad - Nn) * 128 * 2, stream);

    dim3 gg(Mpad / 128, FDIM / 128);

    // Layer 1
    k_gemm_bf16<<<gg, 256, 0, stream>>>(Abf, W1T, Hbf, 256, FDIM);
    k_edge_logits<<<Nn, 128, 0, stream>>>(Hbf, a1s, a1d, e1s, e1d, Nn);
    k_edge_w<<<1024, 256, 0, stream>>>(ssrc, sdst, e1s, e1d, w4, E);
    k_den<<<(Nn + 255) / 256, 256, 0, stream>>>(e1s, e1d, offs, w4, wself, invden, Nn);
    k_gat_mean<<<Nn, 128, 0, stream>>>(Hbf, w4, wself, invden, offs, ssrc, b1, H2in, Nn);

    // Layer 2 (+ fused linear + sigmoid)
    k_gemm_bf16<<<gg, 256, 0, stream>>>(H2in, W2T, Hbf, 128, FDIM);
    k_edge_logits<<<Nn, 128, 0, stream>>>(Hbf, a2s, a2d, e1s, e1d, Nn);
    k_edge_w<<<1024, 256, 0, stream>>>(ssrc, sdst, e1s, e1d, w4, E);
    k_den<<<(Nn + 255) / 256, 256, 0, stream>>>(e1s, e1d, offs, w4, wself, invden, Nn);
    k_gat_cat_final<<<Nn, 128, 0, stream>>>(Hbf, w4, wself, invden, offs, ssrc, b2, Wl, bl, outp, Nn);
}

// Round 5
// 299.327 us; speedup vs baseline: 1.2065x; 1.2065x over previous
//
#include <hip/hip_runtime.h>
#include <stdint.h>

#define HEADS 3
#define HID 128
#define FDIM (HEADS * HID)   // 384

typedef __attribute__((ext_vector_type(8))) short bf16x8;
typedef __attribute__((ext_vector_type(4))) float f32x4;

__device__ __forceinline__ float lrelu(float x) { return x >= 0.f ? x : 0.2f * x; }
__device__ __forceinline__ float rrelu(float x) {
    const float SLOPE = (1.0f / 8.0f + 1.0f / 3.0f) * 0.5f;
    return x >= 0.f ? x : SLOPE * x;
}
__device__ __forceinline__ unsigned short f2bf(float f) {
    union { float f; unsigned u; } c; c.f = f;
    unsigned r = c.u + 0x7FFF + ((c.u >> 16) & 1);   // RNE
    return (unsigned short)(r >> 16);
}
__device__ __forceinline__ float bf2f(unsigned short b) {
    union { unsigned u; float f; } c; c.u = (unsigned)b << 16;
    return c.f;
}
__device__ __forceinline__ float bflo(unsigned u) {
    union { unsigned u; float f; } c; c.u = u << 16; return c.f;
}
__device__ __forceinline__ float bfhi(unsigned u) {
    union { unsigned u; float f; } c; c.u = u & 0xffff0000u; return c.f;
}

__device__ __forceinline__ void gload_lds16(const void* g, void* l) {
    __builtin_amdgcn_global_load_lds(
        (const __attribute__((address_space(1))) void*)g,
        (__attribute__((address_space(3))) void*)l, 16, 0, 0);
}

// ---------------- CSR build (counting sort by dst) ----------------

__global__ void k_hist(const int* __restrict__ dst, int E, int* __restrict__ cnt) {
    for (int i = blockIdx.x * blockDim.x + threadIdx.x; i < E; i += gridDim.x * blockDim.x)
        atomicAdd(&cnt[dst[i]], 1);
}

#define SC_T 256
#define SC_E 8
#define SC_CHUNK (SC_T * SC_E)   // 2048

__global__ __launch_bounds__(SC_T) void k_scan1(const int* __restrict__ cnt,
                                                int* __restrict__ exc,
                                                int* __restrict__ bsum, int n) {
    __shared__ int sm[SC_T];
    int b = blockIdx.x, t = threadIdx.x;
    int base = b * SC_CHUNK + t * SC_E;
    int v[SC_E];
    int s = 0;
#pragma unroll
    for (int i = 0; i < SC_E; i++) {
        int idx = base + i;
        v[i] = (idx < n) ? cnt[idx] : 0;
        s += v[i];
    }
    sm[t] = s;
    __syncthreads();
    for (int off = 1; off < SC_T; off <<= 1) {
        int x = (t >= off) ? sm[t - off] : 0;
        __syncthreads();
        sm[t] += x;
        __syncthreads();
    }
    int run = sm[t] - s;
    if (t == SC_T - 1) bsum[b] = sm[t];
#pragma unroll
    for (int i = 0; i < SC_E; i++) {
        int idx = base + i;
        if (idx < n) exc[idx] = run;
        run += v[i];
    }
}

__global__ __launch_bounds__(256) void k_scan2(const int* __restrict__ bsum,
                                               int* __restrict__ bpre, int nb) {
    __shared__ int sm[256];
    int t = threadIdx.x;
    int v = (t < nb) ? bsum[t] : 0;
    sm[t] = v;
    __syncthreads();
    for (int off = 1; off < 256; off <<= 1) {
        int x = (t >= off) ? sm[t - off] : 0;
        __syncthreads();
        sm[t] += x;
        __syncthreads();
    }
    if (t < nb) bpre[t + 1] = sm[t];
    if (t == 0) bpre[0] = 0;
}

__global__ void k_scan3(int* __restrict__ offs, const int* __restrict__ bpre,
                        int* __restrict__ cursor, int n, int nb) {
    int i = blockIdx.x * blockDim.x + threadIdx.x;
    if (i < n) {
        int o = offs[i] + bpre[i / SC_CHUNK];
        offs[i] = o;
        cursor[i] = o;
    }
    if (i == 0) offs[n] = bpre[nb];
}

__global__ void k_scatter(const int* __restrict__ src, const int* __restrict__ dst, int E,
                          int* __restrict__ cursor, int* __restrict__ ssrc,
                          int* __restrict__ sdst) {
    for (int i = blockIdx.x * blockDim.x + threadIdx.x; i < E; i += gridDim.x * blockDim.x) {
        int d = dst[i];
        int p = atomicAdd(&cursor[d], 1);
        ssrc[p] = src[i];
        sdst[p] = d;
    }
}

// ---------------- bf16 converts ----------------

__global__ void k_cvt_concat(const float* __restrict__ z, const float* __restrict__ x,
                             unsigned short* __restrict__ A, int Nn, int Mpad) {
    int total = Mpad * 64;
    for (int i = blockIdx.x * blockDim.x + threadIdx.x; i < total;
         i += gridDim.x * blockDim.x) {
        int row = i >> 6;
        int c4 = (i & 63) * 4;
        float4 v = make_float4(0.f, 0.f, 0.f, 0.f);
        if (row < Nn) {
            const float* sp = (c4 < 128) ? (z + (size_t)row * 128 + c4)
                                         : (x + (size_t)row * 128 + (c4 - 128));
            v = *(const float4*)sp;
        }
        unsigned short o[4] = {f2bf(v.x), f2bf(v.y), f2bf(v.z), f2bf(v.w)};
        *(uint2*)&A[(size_t)row * 256 + c4] = *(uint2*)o;
    }
}

__global__ void k_cvt_wt(const float* __restrict__ W, unsigned short* __restrict__ WT,
                         int K, int Ncols) {
    int n = blockIdx.x;
    for (int k = threadIdx.x; k < K; k += blockDim.x)
        WT[(size_t)n * K + k] = f2bf(W[(size_t)k * Ncols + n]);
}

// ---------------- bf16 MFMA GEMM ----------------

__global__ __launch_bounds__(256) void k_gemm_bf16(
    const unsigned short* __restrict__ A,
    const unsigned short* __restrict__ BT,
    unsigned short* __restrict__ C,
    int K, int Ncols) {
    __shared__ __align__(16) unsigned short As[128 * 32];
    __shared__ __align__(16) unsigned short Bs[128 * 32];
    int tid = threadIdx.x;
    int w = tid >> 6, lane = tid & 63;
    int row0 = blockIdx.x * 128;
    int col0 = blockIdx.y * 128;
    int wr = w >> 1, wc = w & 1;

    f32x4 acc[4][4] = {};
    int frow = lane & 15;
    int fk = (lane >> 4) * 8;

    for (int k0 = 0; k0 < K; k0 += 32) {
#pragma unroll
        for (int i = 0; i < 2; i++) {
            int c = (i * 4 + w) * 64 + lane;
            gload_lds16(A + (size_t)(row0 + (c >> 2)) * K + k0 + (c & 3) * 8,
                        (char*)As + (i * 4 + w) * 1024);
        }
#pragma unroll
        for (int i = 0; i < 2; i++) {
            int c = (i * 4 + w) * 64 + lane;
            gload_lds16(BT + (size_t)(col0 + (c >> 2)) * K + k0 + (c & 3) * 8,
                        (char*)Bs + (i * 4 + w) * 1024);
        }
        asm volatile("s_waitcnt vmcnt(0)" ::: "memory");
        __syncthreads();

        bf16x8 af[4], bfr[4];
#pragma unroll
        for (int m = 0; m < 4; m++)
            af[m] = *(const bf16x8*)&As[(wr * 64 + m * 16 + frow) * 32 + fk];
#pragma unroll
        for (int n = 0; n < 4; n++)
            bfr[n] = *(const bf16x8*)&Bs[(wc * 64 + n * 16 + frow) * 32 + fk];
#pragma unroll
        for (int m = 0; m < 4; m++)
#pragma unroll
            for (int n = 0; n < 4; n++)
                acc[m][n] = __builtin_amdgcn_mfma_f32_16x16x32_bf16(af[m], bfr[n], acc[m][n], 0, 0, 0);
        __syncthreads();
    }

    int ccol = lane & 15, crow = (lane >> 4) * 4;
#pragma unroll
    for (int m = 0; m < 4; m++)
#pragma unroll
        for (int n = 0; n < 4; n++)
#pragma unroll
            for (int j = 0; j < 4; j++) {
                int r = row0 + wr * 64 + m * 16 + crow + j;
                int cc = col0 + wc * 64 + n * 16 + ccol;
                C[(size_t)r * Ncols + cc] = f2bf(acc[m][n][j]);
            }
}

// ---------------- per-node attention logits (192 thr: wave per head) ----------------

__global__ __launch_bounds__(192) void k_edge_logits(const unsigned short* __restrict__ H,
                                                     const float* __restrict__ asrc,
                                                     const float* __restrict__ adst,
                                                     float* __restrict__ es,
                                                     float* __restrict__ ed, int Nn) {
    int n = blockIdx.x;
    int t = threadIdx.x;
    int h = t >> 6, q = t & 63;
    int col = h * HID + 2 * q;
    unsigned u = *(const unsigned*)&H[(size_t)n * FDIM + col];
    float2 av = *(const float2*)&asrc[col];
    float2 dv = *(const float2*)&adst[col];
    float v0 = bflo(u), v1 = bfhi(u);
    float ps = v0 * av.x + v1 * av.y;
    float pd = v0 * dv.x + v1 * dv.y;
#pragma unroll
    for (int off = 32; off > 0; off >>= 1) {
        ps += __shfl_down(ps, off);
        pd += __shfl_down(pd, off);
    }
    if (q == 0) {
        es[n * HEADS + h] = ps;
        ed[n * HEADS + h] = pd;
    }
}

// ---------------- per-edge weights ----------------

__global__ void k_edge_w(const int* __restrict__ ssrc, const int* __restrict__ sdst,
                         const float* __restrict__ es, const float* __restrict__ ed,
                         float4* __restrict__ w4, int E) {
    for (int j = blockIdx.x * blockDim.x + threadIdx.x; j < E; j += gridDim.x * blockDim.x) {
        int s = ssrc[j], d = sdst[j];
        float w0 = __expf(lrelu(es[s * 3 + 0] + ed[d * 3 + 0]));
        float w1 = __expf(lrelu(es[s * 3 + 1] + ed[d * 3 + 1]));
        float w2 = __expf(lrelu(es[s * 3 + 2] + ed[d * 3 + 2]));
        w4[j] = make_float4(w0, w1, w2, 0.f);
    }
}

// per-node: self weight + inverse denominators (4-unrolled)
__global__ void k_den(const float* __restrict__ es, const float* __restrict__ ed,
                      const int* __restrict__ offs, const float4* __restrict__ w4,
                      float4* __restrict__ wself, float4* __restrict__ invden, int Nn) {
    for (int n = blockIdx.x * blockDim.x + threadIdx.x; n < Nn; n += gridDim.x * blockDim.x) {
        float s0 = __expf(lrelu(es[n * 3 + 0] + ed[n * 3 + 0]));
        float s1 = __expf(lrelu(es[n * 3 + 1] + ed[n * 3 + 1]));
        float s2 = __expf(lrelu(es[n * 3 + 2] + ed[n * 3 + 2]));
        float d0 = s0, d1 = s1, d2 = s2;
        int j0 = offs[n], j1 = offs[n + 1];
        int j = j0;
        for (; j + 4 <= j1; j += 4) {
            float4 a = w4[j], b = w4[j + 1], c = w4[j + 2], d = w4[j + 3];
            d0 += a.x + b.x + c.x + d.x;
            d1 += a.y + b.y + c.y + d.y;
            d2 += a.z + b.z + c.z + d.z;
        }
        for (; j < j1; j++) {
            float4 w = w4[j];
            d0 += w.x; d1 += w.y; d2 += w.z;
        }
        wself[n] = make_float4(s0, s1, s2, 0.f);
        invden[n] = make_float4(1.f / d0, 1.f / d1, 1.f / d2, 0.f);
    }
}

// ---------------- GAT aggregate, layer 1 (192 thr, 4-edge unroll) ----------------

__global__ __launch_bounds__(192) void k_gat_mean(const unsigned short* __restrict__ H,
                                                  const float* __restrict__ w4f,
                                                  const float* __restrict__ wselff,
                                                  const float* __restrict__ invdenf,
                                                  const int* __restrict__ offs,
                                                  const int* __restrict__ ssrc,
                                                  const float* __restrict__ b,
                                                  unsigned short* __restrict__ out, int Nn) {
    int n = blockIdx.x;
    int t = threadIdx.x;
    int h = t >> 6, q = t & 63;
    int cidx = (h * HID + 2 * q) >> 1;           // uint index within row
    const unsigned* Hu = (const unsigned*)H;     // row stride FDIM/2 = 192 uints
    unsigned u = Hu[(size_t)n * 192 + cidx];
    float wsh = wselff[n * 4 + h];
    float a0 = wsh * bflo(u), a1 = wsh * bfhi(u);
    int j0 = offs[n], j1 = offs[n + 1];
    int j = j0;
    for (; j + 4 <= j1; j += 4) {
        int s0 = ssrc[j], s1 = ssrc[j + 1], s2 = ssrc[j + 2], s3 = ssrc[j + 3];
        float w0 = w4f[(size_t)j * 4 + h];
        float w1 = w4f[(size_t)(j + 1) * 4 + h];
        float w2 = w4f[(size_t)(j + 2) * 4 + h];
        float w3 = w4f[(size_t)(j + 3) * 4 + h];
        unsigned u0 = Hu[(size_t)s0 * 192 + cidx];
        unsigned u1 = Hu[(size_t)s1 * 192 + cidx];
        unsigned u2 = Hu[(size_t)s2 * 192 + cidx];
        unsigned u3 = Hu[(size_t)s3 * 192 + cidx];
        a0 = fmaf(w0, bflo(u0), a0); a1 = fmaf(w0, bfhi(u0), a1);
        a0 = fmaf(w1, bflo(u1), a0); a1 = fmaf(w1, bfhi(u1), a1);
        a0 = fmaf(w2, bflo(u2), a0); a1 = fmaf(w2, bfhi(u2), a1);
        a0 = fmaf(w3, bflo(u3), a0); a1 = fmaf(w3, bfhi(u3), a1);
    }
    for (; j < j1; j++) {
        int s = ssrc[j];
        float w = w4f[(size_t)j * 4 + h];
        unsigned uu = Hu[(size_t)s * 192 + cidx];
        a0 = fmaf(w, bflo(uu), a0); a1 = fmaf(w, bfhi(uu), a1);
    }
    float iv = invdenf[n * 4 + h];
    a0 *= iv; a1 *= iv;
    __shared__ float sm[3][128];
    sm[h][2 * q] = a0;
    sm[h][2 * q + 1] = a1;
    __syncthreads();
    if (t < 64) {
        int c0 = 2 * t;
        float m0 = (sm[0][c0] + sm[1][c0] + sm[2][c0]) * (1.f / 3.f) + b[c0];
        float m1 = (sm[0][c0 + 1] + sm[1][c0 + 1] + sm[2][c0 + 1]) * (1.f / 3.f) + b[c0 + 1];
        unsigned short o[2] = {f2bf(rrelu(m0)), f2bf(rrelu(m1))};
        *(unsigned*)&out[(size_t)n * HID + c0] = *(unsigned*)o;
    }
}

// ---------------- GAT aggregate, layer 2 + linear + sigmoid ----------------

__global__ __launch_bounds__(192) void k_gat_cat_final(const unsigned short* __restrict__ H,
                                                       const float* __restrict__ w4f,
                                                       const float* __restrict__ wselff,
                                                       const float* __restrict__ invdenf,
                                                       const int* __restrict__ offs,
                                                       const int* __restrict__ ssrc,
                                                       const float* __restrict__ b,
                                                       const float* __restrict__ Wl,
                                                       const float* __restrict__ bl,
                                                       float* __restrict__ out, int Nn) {
    int n = blockIdx.x;
    int t = threadIdx.x;
    int h = t >> 6, q = t & 63;
    int col = h * HID + 2 * q;
    int cidx = col >> 1;
    const unsigned* Hu = (const unsigned*)H;
    unsigned u = Hu[(size_t)n * 192 + cidx];
    float wsh = wselff[n * 4 + h];
    float a0 = wsh * bflo(u), a1 = wsh * bfhi(u);
    int j0 = offs[n], j1 = offs[n + 1];
    int j = j0;
    for (; j + 4 <= j1; j += 4) {
        int s0 = ssrc[j], s1 = ssrc[j + 1], s2 = ssrc[j + 2], s3 = ssrc[j + 3];
        float w0 = w4f[(size_t)j * 4 + h];
        float w1 = w4f[(size_t)(j + 1) * 4 + h];
        float w2 = w4f[(size_t)(j + 2) * 4 + h];
        float w3 = w4f[(size_t)(j + 3) * 4 + h];
        unsigned u0 = Hu[(size_t)s0 * 192 + cidx];
        unsigned u1 = Hu[(size_t)s1 * 192 + cidx];
        unsigned u2 = Hu[(size_t)s2 * 192 + cidx];
        unsigned u3 = Hu[(size_t)s3 * 192 + cidx];
        a0 = fmaf(w0, bflo(u0), a0); a1 = fmaf(w0, bfhi(u0), a1);
        a0 = fmaf(w1, bflo(u1), a0); a1 = fmaf(w1, bfhi(u1), a1);
        a0 = fmaf(w2, bflo(u2), a0); a1 = fmaf(w2, bfhi(u2), a1);
        a0 = fmaf(w3, bflo(u3), a0); a1 = fmaf(w3, bfhi(u3), a1);
    }
    for (; j < j1; j++) {
        int s = ssrc[j];
        float w = w4f[(size_t)j * 4 + h];
        unsigned uu = Hu[(size_t)s * 192 + cidx];
        a0 = fmaf(w, bflo(uu), a0); a1 = fmaf(w, bfhi(uu), a1);
    }
    float iv = invdenf[n * 4 + h];
    float r0 = rrelu(a0 * iv + b[col]);
    float r1 = rrelu(a1 * iv + b[col + 1]);
    float p = r0 * Wl[col] + r1 * Wl[col + 1];
#pragma unroll
    for (int off = 32; off > 0; off >>= 1) p += __shfl_down(p, off);
    __shared__ float red[3];
    if (q == 0) red[h] = p;
    __syncthreads();
    if (t == 0) out[n] = 1.f / (1.f + __expf(-(red[0] + red[1] + red[2] + bl[0])));
}

// ---------------- launch ----------------

extern "C" void kernel_launch(void* const* d_in, const int* in_sizes, int n_in,
                              void* d_out, int out_size, void* d_ws, size_t ws_size,
                              hipStream_t stream) {
    const float* z   = (const float*)d_in[0];
    const float* x   = (const float*)d_in[1];
    const int*   ei  = (const int*)d_in[2];
    const float* W1  = (const float*)d_in[3];
    const float* a1s = (const float*)d_in[4];
    const float* a1d = (const float*)d_in[5];
    const float* b1  = (const float*)d_in[6];
    const float* W2  = (const float*)d_in[7];
    const float* a2s = (const float*)d_in[8];
    const float* a2d = (const float*)d_in[9];
    const float* b2  = (const float*)d_in[10];
    const float* Wl  = (const float*)d_in[11];
    const float* bl  = (const float*)d_in[12];
    float* outp = (float*)d_out;

    int Nn = in_sizes[0] / 128;
    int E  = in_sizes[2] / 2;
    int Mpad = (Nn + 127) & ~127;
    int nb = (Nn + SC_CHUNK - 1) / SC_CHUNK;

    char* p = (char*)d_ws;
    auto carve = [&](size_t bytes) -> char* {
        char* r = p;
        p += (bytes + 255) & ~(size_t)255;
        return r;
    };
    int*            offs   = (int*)carve((size_t)(Nn + 1) * 4);
    int*            cursor = (int*)carve((size_t)Nn * 4);
    int*            ssrc   = (int*)carve((size_t)E * 4);
    int*            sdst   = (int*)carve((size_t)E * 4);
    int*            bsum   = (int*)carve((size_t)(nb + 1) * 4);
    int*            bpre   = (int*)carve((size_t)(nb + 1) * 4);
    float*          e1s    = (float*)carve((size_t)Nn * 3 * 4);
    float*          e1d    = (float*)carve((size_t)Nn * 3 * 4);
    float4*         w4     = (float4*)carve((size_t)E * 16);
    float4*         wself  = (float4*)carve((size_t)Nn * 16);
    float4*         invden = (float4*)carve((size_t)Nn * 16);
    unsigned short* Abf    = (unsigned short*)carve((size_t)Mpad * 256 * 2);
    unsigned short* W1T    = (unsigned short*)carve((size_t)FDIM * 256 * 2);
    unsigned short* W2T    = (unsigned short*)carve((size_t)FDIM * 128 * 2);
    unsigned short* Hbf    = (unsigned short*)carve((size_t)Mpad * FDIM * 2);
    unsigned short* H2in   = (unsigned short*)carve((size_t)Mpad * 128 * 2);

    const int* srcI = ei;
    const int* dstI = ei + E;

    // CSR build
    hipMemsetAsync(cursor, 0, (size_t)Nn * 4, stream);
    k_hist<<<256, 256, 0, stream>>>(dstI, E, cursor);
    k_scan1<<<nb, SC_T, 0, stream>>>(cursor, offs, bsum, Nn);
    k_scan2<<<1, 256, 0, stream>>>(bsum, bpre, nb);
    k_scan3<<<(Nn + 255) / 256, 256, 0, stream>>>(offs, bpre, cursor, Nn, nb);
    k_scatter<<<256, 256, 0, stream>>>(srcI, dstI, E, cursor, ssrc, sdst);

    // bf16 converts
    k_cvt_concat<<<2048, 256, 0, stream>>>(z, x, Abf, Nn, Mpad);
    k_cvt_wt<<<FDIM, 256, 0, stream>>>(W1, W1T, 256, FDIM);
    k_cvt_wt<<<FDIM, 128, 0, stream>>>(W2, W2T, 128, FDIM);
    hipMemsetAsync(H2in + (size_t)Nn * 128, 0, (size_t)(Mpad - Nn) * 128 * 2, stream);

    dim3 gg(Mpad / 128, FDIM / 128);

    // Layer 1
    k_gemm_bf16<<<gg, 256, 0, stream>>>(Abf, W1T, Hbf, 256, FDIM);
    k_edge_logits<<<Nn, 192, 0, stream>>>(Hbf, a1s, a1d, e1s, e1d, Nn);
    k_edge_w<<<1024, 256, 0, stream>>>(ssrc, sdst, e1s, e1d, w4, E);
    k_den<<<(Nn + 255) / 256, 256, 0, stream>>>(e1s, e1d, offs, w4, wself, invden, Nn);
    k_gat_mean<<<Nn, 192, 0, stream>>>(Hbf, (const float*)w4, (const float*)wself,
                                       (const float*)invden, offs, ssrc, b1, H2in, Nn);

    // Layer 2 (+ fused linear + sigmoid)
    k_gemm_bf16<<<gg, 256, 0, stream>>>(H2in, W2T, Hbf, 128, FDIM);
    k_edge_logits<<<Nn, 192, 0, stream>>>(Hbf, a2s, a2d, e1s, e1d, Nn);
    k_edge_w<<<1024, 256, 0, stream>>>(ssrc, sdst, e1s, e1d, w4, E);
    k_den<<<(Nn + 255) / 256, 256, 0, stream>>>(e1s, e1d, offs, w4, wself, invden, Nn);
    k_gat_cat_final<<<Nn, 192, 0, stream>>>(Hbf, (const float*)w4, (const float*)wself,
                                            (const float*)invden, offs, ssrc, b2, Wl, bl,
                                            outp, Nn);
}

// Round 6
// 267.245 us; speedup vs baseline: 1.3514x; 1.1200x over previous
//
#include <hip/hip_runtime.h>
#include <stdint.h>

#define HEADS 3
#define HID 128
#define FDIM (HEADS * HID)   // 384

typedef __attribute__((ext_vector_type(8))) short bf16x8;
typedef __attribute__((ext_vector_type(4))) float f32x4;

__device__ __forceinline__ float lrelu(float x) { return x >= 0.f ? x : 0.2f * x; }
__device__ __forceinline__ float rrelu(float x) {
    const float SLOPE = (1.0f / 8.0f + 1.0f / 3.0f) * 0.5f;
    return x >= 0.f ? x : SLOPE * x;
}
__device__ __forceinline__ unsigned short f2bf(float f) {
    union { float f; unsigned u; } c; c.f = f;
    unsigned r = c.u + 0x7FFF + ((c.u >> 16) & 1);   // RNE
    return (unsigned short)(r >> 16);
}
__device__ __forceinline__ float bflo(unsigned u) {
    union { unsigned u; float f; } c; c.u = u << 16; return c.f;
}
__device__ __forceinline__ float bfhi(unsigned u) {
    union { unsigned u; float f; } c; c.u = u & 0xffff0000u; return c.f;
}

__device__ __forceinline__ void gload_lds16(const void* g, void* l) {
    __builtin_amdgcn_global_load_lds(
        (const __attribute__((address_space(1))) void*)g,
        (__attribute__((address_space(3))) void*)l, 16, 0, 0);
}

// ---------------- CSR build (counting sort by dst) ----------------

__global__ void k_hist(const int* __restrict__ dst, int E, int* __restrict__ cnt) {
    for (int i = blockIdx.x * blockDim.x + threadIdx.x; i < E; i += gridDim.x * blockDim.x)
        atomicAdd(&cnt[dst[i]], 1);
}

#define SC_T 256
#define SC_E 8
#define SC_CHUNK (SC_T * SC_E)   // 2048

__global__ __launch_bounds__(SC_T) void k_scan1(const int* __restrict__ cnt,
                                                int* __restrict__ exc,
                                                int* __restrict__ bsum, int n) {
    __shared__ int sm[SC_T];
    int b = blockIdx.x, t = threadIdx.x;
    int base = b * SC_CHUNK + t * SC_E;
    int v[SC_E];
    int s = 0;
#pragma unroll
    for (int i = 0; i < SC_E; i++) {
        int idx = base + i;
        v[i] = (idx < n) ? cnt[idx] : 0;
        s += v[i];
    }
    sm[t] = s;
    __syncthreads();
    for (int off = 1; off < SC_T; off <<= 1) {
        int x = (t >= off) ? sm[t - off] : 0;
        __syncthreads();
        sm[t] += x;
        __syncthreads();
    }
    int run = sm[t] - s;
    if (t == SC_T - 1) bsum[b] = sm[t];
#pragma unroll
    for (int i = 0; i < SC_E; i++) {
        int idx = base + i;
        if (idx < n) exc[idx] = run;
        run += v[i];
    }
}

__global__ __launch_bounds__(256) void k_scan2(const int* __restrict__ bsum,
                                               int* __restrict__ bpre, int nb) {
    __shared__ int sm[256];
    int t = threadIdx.x;
    int v = (t < nb) ? bsum[t] : 0;
    sm[t] = v;
    __syncthreads();
    for (int off = 1; off < 256; off <<= 1) {
        int x = (t >= off) ? sm[t - off] : 0;
        __syncthreads();
        sm[t] += x;
        __syncthreads();
    }
    if (t < nb) bpre[t + 1] = sm[t];
    if (t == 0) bpre[0] = 0;
}

__global__ void k_scan3(int* __restrict__ offs, const int* __restrict__ bpre,
                        int* __restrict__ cursor, int n, int nb) {
    int i = blockIdx.x * blockDim.x + threadIdx.x;
    if (i < n) {
        int o = offs[i] + bpre[i / SC_CHUNK];
        offs[i] = o;
        cursor[i] = o;
    }
    if (i == 0) offs[n] = bpre[nb];
}

__global__ void k_scatter(const int* __restrict__ src, const int* __restrict__ dst, int E,
                          int* __restrict__ cursor, int* __restrict__ ssrc,
                          int* __restrict__ sdst) {
    for (int i = blockIdx.x * blockDim.x + threadIdx.x; i < E; i += gridDim.x * blockDim.x) {
        int d = dst[i];
        int p = atomicAdd(&cursor[d], 1);
        ssrc[p] = src[i];
        sdst[p] = d;
    }
}

// ---------------- bf16 converts ----------------

__global__ void k_cvt_concat(const float* __restrict__ z, const float* __restrict__ x,
                             unsigned short* __restrict__ A, int Nn, int Mpad) {
    int total = Mpad * 64;
    for (int i = blockIdx.x * blockDim.x + threadIdx.x; i < total;
         i += gridDim.x * blockDim.x) {
        int row = i >> 6;
        int c4 = (i & 63) * 4;
        float4 v = make_float4(0.f, 0.f, 0.f, 0.f);
        if (row < Nn) {
            const float* sp = (c4 < 128) ? (z + (size_t)row * 128 + c4)
                                         : (x + (size_t)row * 128 + (c4 - 128));
            v = *(const float4*)sp;
        }
        unsigned short o[4] = {f2bf(v.x), f2bf(v.y), f2bf(v.z), f2bf(v.w)};
        *(uint2*)&A[(size_t)row * 256 + c4] = *(uint2*)o;
    }
}

__global__ void k_cvt_wt(const float* __restrict__ W, unsigned short* __restrict__ WT,
                         int K, int Ncols) {
    int n = blockIdx.x;
    for (int k = threadIdx.x; k < K; k += blockDim.x)
        WT[(size_t)n * K + k] = f2bf(W[(size_t)k * Ncols + n]);
}

// ---------------- bf16 MFMA GEMM + fused per-head logits epilogue ----------------
// col block == head (Ncols = 384, 128 cols/block).

__global__ __launch_bounds__(256) void k_gemm_bf16(
    const unsigned short* __restrict__ A,
    const unsigned short* __restrict__ BT,
    unsigned short* __restrict__ C,
    int K, int Ncols,
    const float* __restrict__ asrc, const float* __restrict__ adst,
    float* __restrict__ es, float* __restrict__ ed, int Nnodes) {
    __shared__ __align__(16) unsigned short As[128 * 32];
    __shared__ __align__(16) unsigned short Bs[128 * 32];
    __shared__ float esP[128][2], edP[128][2];
    int tid = threadIdx.x;
    int w = tid >> 6, lane = tid & 63;
    int row0 = blockIdx.x * 128;
    int col0 = blockIdx.y * 128;
    int wr = w >> 1, wc = w & 1;

    f32x4 acc[4][4] = {};
    int frow = lane & 15;
    int fk = (lane >> 4) * 8;

    for (int k0 = 0; k0 < K; k0 += 32) {
#pragma unroll
        for (int i = 0; i < 2; i++) {
            int c = (i * 4 + w) * 64 + lane;
            gload_lds16(A + (size_t)(row0 + (c >> 2)) * K + k0 + (c & 3) * 8,
                        (char*)As + (i * 4 + w) * 1024);
        }
#pragma unroll
        for (int i = 0; i < 2; i++) {
            int c = (i * 4 + w) * 64 + lane;
            gload_lds16(BT + (size_t)(col0 + (c >> 2)) * K + k0 + (c & 3) * 8,
                        (char*)Bs + (i * 4 + w) * 1024);
        }
        asm volatile("s_waitcnt vmcnt(0)" ::: "memory");
        __syncthreads();

        bf16x8 af[4], bfr[4];
#pragma unroll
        for (int m = 0; m < 4; m++)
            af[m] = *(const bf16x8*)&As[(wr * 64 + m * 16 + frow) * 32 + fk];
#pragma unroll
        for (int n = 0; n < 4; n++)
            bfr[n] = *(const bf16x8*)&Bs[(wc * 64 + n * 16 + frow) * 32 + fk];
#pragma unroll
        for (int m = 0; m < 4; m++)
#pragma unroll
            for (int n = 0; n < 4; n++)
                acc[m][n] = __builtin_amdgcn_mfma_f32_16x16x32_bf16(af[m], bfr[n], acc[m][n], 0, 0, 0);
        __syncthreads();
    }

    int ccol = lane & 15, crow = (lane >> 4) * 4;

    // C write
#pragma unroll
    for (int m = 0; m < 4; m++)
#pragma unroll
        for (int n = 0; n < 4; n++)
#pragma unroll
            for (int j = 0; j < 4; j++) {
                int r = row0 + wr * 64 + m * 16 + crow + j;
                int cc = col0 + wc * 64 + n * 16 + ccol;
                C[(size_t)r * Ncols + cc] = f2bf(acc[m][n][j]);
            }

    // fused logits: es/ed[row, head] from fp32 acc
    int head = blockIdx.y;
    float as4[4], ad4[4];
#pragma unroll
    for (int n = 0; n < 4; n++) {
        int col_sub = wc * 64 + n * 16 + ccol;
        as4[n] = asrc[head * HID + col_sub];
        ad4[n] = adst[head * HID + col_sub];
    }
#pragma unroll
    for (int m = 0; m < 4; m++)
#pragma unroll
        for (int j = 0; j < 4; j++) {
            float ps = 0.f, pd = 0.f;
#pragma unroll
            for (int n = 0; n < 4; n++) {
                float v = acc[m][n][j];
                ps = fmaf(v, as4[n], ps);
                pd = fmaf(v, ad4[n], pd);
            }
#pragma unroll
            for (int off = 1; off < 16; off <<= 1) {
                ps += __shfl_xor(ps, off);
                pd += __shfl_xor(pd, off);
            }
            if (ccol == 0) {
                int row_sub = wr * 64 + m * 16 + crow + j;
                esP[row_sub][wc] = ps;
                edP[row_sub][wc] = pd;
            }
        }
    __syncthreads();
    if (tid < 128) {
        int r = row0 + tid;
        if (r < Nnodes) {
            es[(size_t)r * 3 + head] = esP[tid][0] + esP[tid][1];
            ed[(size_t)r * 3 + head] = edP[tid][0] + edP[tid][1];
        }
    }
}

// ---------------- per-edge weights ----------------

__global__ void k_edge_w(const int* __restrict__ ssrc, const int* __restrict__ sdst,
                         const float* __restrict__ es, const float* __restrict__ ed,
                         float4* __restrict__ w4, int E) {
    for (int j = blockIdx.x * blockDim.x + threadIdx.x; j < E; j += gridDim.x * blockDim.x) {
        int s = ssrc[j], d = sdst[j];
        float w0 = __expf(lrelu(es[s * 3 + 0] + ed[d * 3 + 0]));
        float w1 = __expf(lrelu(es[s * 3 + 1] + ed[d * 3 + 1]));
        float w2 = __expf(lrelu(es[s * 3 + 2] + ed[d * 3 + 2]));
        w4[j] = make_float4(w0, w1, w2, 0.f);
    }
}

// per-node: self weight + inverse denominators
__global__ void k_den(const float* __restrict__ es, const float* __restrict__ ed,
                      const int* __restrict__ offs, const float4* __restrict__ w4,
                      float4* __restrict__ wself, float4* __restrict__ invden, int Nn) {
    for (int n = blockIdx.x * blockDim.x + threadIdx.x; n < Nn; n += gridDim.x * blockDim.x) {
        float s0 = __expf(lrelu(es[n * 3 + 0] + ed[n * 3 + 0]));
        float s1 = __expf(lrelu(es[n * 3 + 1] + ed[n * 3 + 1]));
        float s2 = __expf(lrelu(es[n * 3 + 2] + ed[n * 3 + 2]));
        float d0 = s0, d1 = s1, d2 = s2;
        int j0 = offs[n], j1 = offs[n + 1];
        int j = j0;
        for (; j + 4 <= j1; j += 4) {
            float4 a = w4[j], b = w4[j + 1], c = w4[j + 2], d = w4[j + 3];
            d0 += a.x + b.x + c.x + d.x;
            d1 += a.y + b.y + c.y + d.y;
            d2 += a.z + b.z + c.z + d.z;
        }
        for (; j < j1; j++) {
            float4 w = w4[j];
            d0 += w.x; d1 += w.y; d2 += w.z;
        }
        wself[n] = make_float4(s0, s1, s2, 0.f);
        invden[n] = make_float4(1.f / d0, 1.f / d1, 1.f / d2, 0.f);
    }
}

// ---------------- GAT aggregate, layer 1 (192 thr, 8-deep pipeline) ----------------

#define AGG_BODY(acc_update)                                                      \
    int j = j0;                                                                   \
    for (; j + 8 <= j1; j += 8) {                                                 \
        int s[8]; float wv[8]; unsigned uu[8];                                    \
        _Pragma("unroll") for (int e = 0; e < 8; e++) s[e] = ssrc[j + e];         \
        _Pragma("unroll") for (int e = 0; e < 8; e++)                             \
            wv[e] = w4f[(size_t)(j + e) * 4 + h];                                 \
        _Pragma("unroll") for (int e = 0; e < 8; e++)                             \
            uu[e] = Hu[(size_t)s[e] * 192 + cidx];                                \
        _Pragma("unroll") for (int e = 0; e < 8; e++) { acc_update(wv[e], uu[e]) }\
    }                                                                             \
    for (; j + 4 <= j1; j += 4) {                                                 \
        int s[4]; float wv[4]; unsigned uu[4];                                    \
        _Pragma("unroll") for (int e = 0; e < 4; e++) s[e] = ssrc[j + e];         \
        _Pragma("unroll") for (int e = 0; e < 4; e++)                             \
            wv[e] = w4f[(size_t)(j + e) * 4 + h];                                 \
        _Pragma("unroll") for (int e = 0; e < 4; e++)                             \
            uu[e] = Hu[(size_t)s[e] * 192 + cidx];                                \
        _Pragma("unroll") for (int e = 0; e < 4; e++) { acc_update(wv[e], uu[e]) }\
    }                                                                             \
    for (; j < j1; j++) {                                                         \
        int s = ssrc[j];                                                          \
        float w = w4f[(size_t)j * 4 + h];                                         \
        unsigned u1 = Hu[(size_t)s * 192 + cidx];                                 \
        { acc_update(w, u1) }                                                     \
    }

#define ACC_UPD(wv, uv) a0 = fmaf(wv, bflo(uv), a0); a1 = fmaf(wv, bfhi(uv), a1);

__global__ __launch_bounds__(192) void k_gat_mean(const unsigned short* __restrict__ H,
                                                  const float* __restrict__ w4f,
                                                  const float* __restrict__ wselff,
                                                  const float* __restrict__ invdenf,
                                                  const int* __restrict__ offs,
                                                  const int* __restrict__ ssrc,
                                                  const float* __restrict__ b,
                                                  unsigned short* __restrict__ out, int Nn) {
    int n = blockIdx.x;
    int t = threadIdx.x;
    int h = t >> 6, q = t & 63;
    int cidx = (h * HID + 2 * q) >> 1;
    const unsigned* Hu = (const unsigned*)H;
    unsigned u = Hu[(size_t)n * 192 + cidx];
    float wsh = wselff[n * 4 + h];
    float a0 = wsh * bflo(u), a1 = wsh * bfhi(u);
    int j0 = offs[n], j1 = offs[n + 1];
    AGG_BODY(ACC_UPD)
    float iv = invdenf[n * 4 + h];
    a0 *= iv; a1 *= iv;
    __shared__ float sm[3][128];
    sm[h][2 * q] = a0;
    sm[h][2 * q + 1] = a1;
    __syncthreads();
    if (t < 64) {
        int c0 = 2 * t;
        float m0 = (sm[0][c0] + sm[1][c0] + sm[2][c0]) * (1.f / 3.f) + b[c0];
        float m1 = (sm[0][c0 + 1] + sm[1][c0 + 1] + sm[2][c0 + 1]) * (1.f / 3.f) + b[c0 + 1];
        unsigned short o[2] = {f2bf(rrelu(m0)), f2bf(rrelu(m1))};
        *(unsigned*)&out[(size_t)n * HID + c0] = *(unsigned*)o;
    }
}

// ---------------- GAT aggregate, layer 2 + linear + sigmoid ----------------

__global__ __launch_bounds__(192) void k_gat_cat_final(const unsigned short* __restrict__ H,
                                                       const float* __restrict__ w4f,
                                                       const float* __restrict__ wselff,
                                                       const float* __restrict__ invdenf,
                                                       const int* __restrict__ offs,
                                                       const int* __restrict__ ssrc,
                                                       const float* __restrict__ b,
                                                       const float* __restrict__ Wl,
                                                       const float* __restrict__ bl,
                                                       float* __restrict__ out, int Nn) {
    int n = blockIdx.x;
    int t = threadIdx.x;
    int h = t >> 6, q = t & 63;
    int col = h * HID + 2 * q;
    int cidx = col >> 1;
    const unsigned* Hu = (const unsigned*)H;
    unsigned u = Hu[(size_t)n * 192 + cidx];
    float wsh = wselff[n * 4 + h];
    float a0 = wsh * bflo(u), a1 = wsh * bfhi(u);
    int j0 = offs[n], j1 = offs[n + 1];
    AGG_BODY(ACC_UPD)
    float iv = invdenf[n * 4 + h];
    float r0 = rrelu(a0 * iv + b[col]);
    float r1 = rrelu(a1 * iv + b[col + 1]);
    float p = r0 * Wl[col] + r1 * Wl[col + 1];
#pragma unroll
    for (int off = 32; off > 0; off >>= 1) p += __shfl_down(p, off);
    __shared__ float red[3];
    if (q == 0) red[h] = p;
    __syncthreads();
    if (t == 0) out[n] = 1.f / (1.f + __expf(-(red[0] + red[1] + red[2] + bl[0])));
}

// ---------------- launch ----------------

extern "C" void kernel_launch(void* const* d_in, const int* in_sizes, int n_in,
                              void* d_out, int out_size, void* d_ws, size_t ws_size,
                              hipStream_t stream) {
    const float* z   = (const float*)d_in[0];
    const float* x   = (const float*)d_in[1];
    const int*   ei  = (const int*)d_in[2];
    const float* W1  = (const float*)d_in[3];
    const float* a1s = (const float*)d_in[4];
    const float* a1d = (const float*)d_in[5];
    const float* b1  = (const float*)d_in[6];
    const float* W2  = (const float*)d_in[7];
    const float* a2s = (const float*)d_in[8];
    const float* a2d = (const float*)d_in[9];
    const float* b2  = (const float*)d_in[10];
    const float* Wl  = (const float*)d_in[11];
    const float* bl  = (const float*)d_in[12];
    float* outp = (float*)d_out;

    int Nn = in_sizes[0] / 128;
    int E  = in_sizes[2] / 2;
    int Mpad = (Nn + 127) & ~127;
    int nb = (Nn + SC_CHUNK - 1) / SC_CHUNK;

    char* p = (char*)d_ws;
    auto carve = [&](size_t bytes) -> char* {
        char* r = p;
        p += (bytes + 255) & ~(size_t)255;
        return r;
    };
    int*            offs   = (int*)carve((size_t)(Nn + 1) * 4);
    int*            cursor = (int*)carve((size_t)Nn * 4);
    int*            ssrc   = (int*)carve((size_t)E * 4);
    int*            sdst   = (int*)carve((size_t)E * 4);
    int*            bsum   = (int*)carve((size_t)(nb + 1) * 4);
    int*            bpre   = (int*)carve((size_t)(nb + 1) * 4);
    float*          e1s    = (float*)carve((size_t)Nn * 3 * 4);
    float*          e1d    = (float*)carve((size_t)Nn * 3 * 4);
    float4*         w4     = (float4*)carve((size_t)E * 16);
    float4*         wself  = (float4*)carve((size_t)Nn * 16);
    float4*         invden = (float4*)carve((size_t)Nn * 16);
    unsigned short* Abf    = (unsigned short*)carve((size_t)Mpad * 256 * 2);
    unsigned short* W1T    = (unsigned short*)carve((size_t)FDIM * 256 * 2);
    unsigned short* W2T    = (unsigned short*)carve((size_t)FDIM * 128 * 2);
    unsigned short* Hbf    = (unsigned short*)carve((size_t)Mpad * FDIM * 2);
    unsigned short* H2in   = (unsigned short*)carve((size_t)Mpad * 128 * 2);

    const int* srcI = ei;
    const int* dstI = ei + E;

    // CSR build
    hipMemsetAsync(cursor, 0, (size_t)Nn * 4, stream);
    k_hist<<<256, 256, 0, stream>>>(dstI, E, cursor);
    k_scan1<<<nb, SC_T, 0, stream>>>(cursor, offs, bsum, Nn);
    k_scan2<<<1, 256, 0, stream>>>(bsum, bpre, nb);
    k_scan3<<<(Nn + 255) / 256, 256, 0, stream>>>(offs, bpre, cursor, Nn, nb);
    k_scatter<<<256, 256, 0, stream>>>(srcI, dstI, E, cursor, ssrc, sdst);

    // bf16 converts
    k_cvt_concat<<<2048, 256, 0, stream>>>(z, x, Abf, Nn, Mpad);
    k_cvt_wt<<<FDIM, 256, 0, stream>>>(W1, W1T, 256, FDIM);
    k_cvt_wt<<<FDIM, 128, 0, stream>>>(W2, W2T, 128, FDIM);
    hipMemsetAsync(H2in + (size_t)Nn * 128, 0, (size_t)(Mpad - Nn) * 128 * 2, stream);

    dim3 gg(Mpad / 128, FDIM / 128);

    // Layer 1 (GEMM + fused logits)
    k_gemm_bf16<<<gg, 256, 0, stream>>>(Abf, W1T, Hbf, 256, FDIM, a1s, a1d, e1s, e1d, Nn);
    k_edge_w<<<1024, 256, 0, stream>>>(ssrc, sdst, e1s, e1d, w4, E);
    k_den<<<(Nn + 255) / 256, 256, 0, stream>>>(e1s, e1d, offs, w4, wself, invden, Nn);
    k_gat_mean<<<Nn, 192, 0, stream>>>(Hbf, (const float*)w4, (const float*)wself,
                                       (const float*)invden, offs, ssrc, b1, H2in, Nn);

    // Layer 2 (GEMM + fused logits, then aggregate + linear + sigmoid)
    k_gemm_bf16<<<gg, 256, 0, stream>>>(H2in, W2T, Hbf, 128, FDIM, a2s, a2d, e1s, e1d, Nn);
    k_edge_w<<<1024, 256, 0, stream>>>(ssrc, sdst, e1s, e1d, w4, E);
    k_den<<<(Nn + 255) / 256, 256, 0, stream>>>(e1s, e1d, offs, w4, wself, invden, Nn);
    k_gat_cat_final<<<Nn, 192, 0, stream>>>(Hbf, (const float*)w4, (const float*)wself,
                                            (const float*)invden, offs, ssrc, b2, Wl, bl,
                                            outp, Nn);
}

// Round 7
// 266.657 us; speedup vs baseline: 1.3544x; 1.0022x over previous
//
#include <hip/hip_runtime.h>
#include <stdint.h>

#define HEADS 3
#define HID 128
#define FDIM (HEADS * HID)   // 384

typedef __attribute__((ext_vector_type(8))) short bf16x8;
typedef __attribute__((ext_vector_type(4))) float f32x4;

__device__ __forceinline__ float lrelu(float x) { return x >= 0.f ? x : 0.2f * x; }
__device__ __forceinline__ float rrelu(float x) {
    const float SLOPE = (1.0f / 8.0f + 1.0f / 3.0f) * 0.5f;
    return x >= 0.f ? x : SLOPE * x;
}
__device__ __forceinline__ unsigned short f2bf(float f) {
    union { float f; unsigned u; } c; c.f = f;
    unsigned r = c.u + 0x7FFF + ((c.u >> 16) & 1);   // RNE
    return (unsigned short)(r >> 16);
}
__device__ __forceinline__ float bflo(unsigned u) {
    union { unsigned u; float f; } c; c.u = u << 16; return c.f;
}
__device__ __forceinline__ float bfhi(unsigned u) {
    union { unsigned u; float f; } c; c.u = u & 0xffff0000u; return c.f;
}

__device__ __forceinline__ void gload_lds16(const void* g, void* l) {
    __builtin_amdgcn_global_load_lds(
        (const __attribute__((address_space(1))) void*)g,
        (__attribute__((address_space(3))) void*)l, 16, 0, 0);
}

// ---------------- CSR build (counting sort by dst) ----------------

__global__ void k_hist(const int* __restrict__ dst, int E, int* __restrict__ cnt) {
    for (int i = blockIdx.x * blockDim.x + threadIdx.x; i < E; i += gridDim.x * blockDim.x)
        atomicAdd(&cnt[dst[i]], 1);
}

#define SC_T 256
#define SC_E 8
#define SC_CHUNK (SC_T * SC_E)   // 2048

__global__ __launch_bounds__(SC_T) void k_scan1(const int* __restrict__ cnt,
                                                int* __restrict__ exc,
                                                int* __restrict__ bsum, int n) {
    __shared__ int sm[SC_T];
    int b = blockIdx.x, t = threadIdx.x;
    int base = b * SC_CHUNK + t * SC_E;
    int v[SC_E];
    int s = 0;
#pragma unroll
    for (int i = 0; i < SC_E; i++) {
        int idx = base + i;
        v[i] = (idx < n) ? cnt[idx] : 0;
        s += v[i];
    }
    sm[t] = s;
    __syncthreads();
    for (int off = 1; off < SC_T; off <<= 1) {
        int x = (t >= off) ? sm[t - off] : 0;
        __syncthreads();
        sm[t] += x;
        __syncthreads();
    }
    int run = sm[t] - s;
    if (t == SC_T - 1) bsum[b] = sm[t];
#pragma unroll
    for (int i = 0; i < SC_E; i++) {
        int idx = base + i;
        if (idx < n) exc[idx] = run;
        run += v[i];
    }
}

__global__ __launch_bounds__(256) void k_scan2(const int* __restrict__ bsum,
                                               int* __restrict__ bpre, int nb) {
    __shared__ int sm[256];
    int t = threadIdx.x;
    int v = (t < nb) ? bsum[t] : 0;
    sm[t] = v;
    __syncthreads();
    for (int off = 1; off < 256; off <<= 1) {
        int x = (t >= off) ? sm[t - off] : 0;
        __syncthreads();
        sm[t] += x;
        __syncthreads();
    }
    if (t < nb) bpre[t + 1] = sm[t];
    if (t == 0) bpre[0] = 0;
}

__global__ void k_scan3(int* __restrict__ offs, const int* __restrict__ bpre,
                        int* __restrict__ cursor, int n, int nb) {
    int i = blockIdx.x * blockDim.x + threadIdx.x;
    if (i < n) {
        int o = offs[i] + bpre[i / SC_CHUNK];
        offs[i] = o;
        cursor[i] = o;
    }
    if (i == 0) offs[n] = bpre[nb];
}

__global__ void k_scatter(const int* __restrict__ src, const int* __restrict__ dst, int E,
                          int* __restrict__ cursor, int* __restrict__ ssrc,
                          int* __restrict__ sdst) {
    for (int i = blockIdx.x * blockDim.x + threadIdx.x; i < E; i += gridDim.x * blockDim.x) {
        int d = dst[i];
        int p = atomicAdd(&cursor[d], 1);
        ssrc[p] = src[i];
        sdst[p] = d;
    }
}

// ---------------- bf16 converts ----------------

__global__ void k_cvt_concat(const float* __restrict__ z, const float* __restrict__ x,
                             unsigned short* __restrict__ A, int Nn, int Mpad) {
    int total = Mpad * 64;
    for (int i = blockIdx.x * blockDim.x + threadIdx.x; i < total;
         i += gridDim.x * blockDim.x) {
        int row = i >> 6;
        int c4 = (i & 63) * 4;
        float4 v = make_float4(0.f, 0.f, 0.f, 0.f);
        if (row < Nn) {
            const float* sp = (c4 < 128) ? (z + (size_t)row * 128 + c4)
                                         : (x + (size_t)row * 128 + (c4 - 128));
            v = *(const float4*)sp;
        }
        unsigned short o[4] = {f2bf(v.x), f2bf(v.y), f2bf(v.z), f2bf(v.w)};
        *(uint2*)&A[(size_t)row * 256 + c4] = *(uint2*)o;
    }
}

__global__ void k_cvt_wt(const float* __restrict__ W, unsigned short* __restrict__ WT,
                         int K, int Ncols) {
    int n = blockIdx.x;
    for (int k = threadIdx.x; k < K; k += blockDim.x)
        WT[(size_t)n * K + k] = f2bf(W[(size_t)k * Ncols + n]);
}

// ---------------- bf16 MFMA GEMM + fused per-head logits epilogue ----------------

__global__ __launch_bounds__(256) void k_gemm_bf16(
    const unsigned short* __restrict__ A,
    const unsigned short* __restrict__ BT,
    unsigned short* __restrict__ C,
    int K, int Ncols,
    const float* __restrict__ asrc, const float* __restrict__ adst,
    float* __restrict__ es, float* __restrict__ ed, int Nnodes) {
    __shared__ __align__(16) unsigned short As[128 * 32];
    __shared__ __align__(16) unsigned short Bs[128 * 32];
    __shared__ float esP[128][2], edP[128][2];
    int tid = threadIdx.x;
    int w = tid >> 6, lane = tid & 63;
    int row0 = blockIdx.x * 128;
    int col0 = blockIdx.y * 128;
    int wr = w >> 1, wc = w & 1;

    f32x4 acc[4][4] = {};
    int frow = lane & 15;
    int fk = (lane >> 4) * 8;

    for (int k0 = 0; k0 < K; k0 += 32) {
#pragma unroll
        for (int i = 0; i < 2; i++) {
            int c = (i * 4 + w) * 64 + lane;
            gload_lds16(A + (size_t)(row0 + (c >> 2)) * K + k0 + (c & 3) * 8,
                        (char*)As + (i * 4 + w) * 1024);
        }
#pragma unroll
        for (int i = 0; i < 2; i++) {
            int c = (i * 4 + w) * 64 + lane;
            gload_lds16(BT + (size_t)(col0 + (c >> 2)) * K + k0 + (c & 3) * 8,
                        (char*)Bs + (i * 4 + w) * 1024);
        }
        asm volatile("s_waitcnt vmcnt(0)" ::: "memory");
        __syncthreads();

        bf16x8 af[4], bfr[4];
#pragma unroll
        for (int m = 0; m < 4; m++)
            af[m] = *(const bf16x8*)&As[(wr * 64 + m * 16 + frow) * 32 + fk];
#pragma unroll
        for (int n = 0; n < 4; n++)
            bfr[n] = *(const bf16x8*)&Bs[(wc * 64 + n * 16 + frow) * 32 + fk];
#pragma unroll
        for (int m = 0; m < 4; m++)
#pragma unroll
            for (int n = 0; n < 4; n++)
                acc[m][n] = __builtin_amdgcn_mfma_f32_16x16x32_bf16(af[m], bfr[n], acc[m][n], 0, 0, 0);
        __syncthreads();
    }

    int ccol = lane & 15, crow = (lane >> 4) * 4;

#pragma unroll
    for (int m = 0; m < 4; m++)
#pragma unroll
        for (int n = 0; n < 4; n++)
#pragma unroll
            for (int j = 0; j < 4; j++) {
                int r = row0 + wr * 64 + m * 16 + crow + j;
                int cc = col0 + wc * 64 + n * 16 + ccol;
                C[(size_t)r * Ncols + cc] = f2bf(acc[m][n][j]);
            }

    int head = blockIdx.y;
    float as4[4], ad4[4];
#pragma unroll
    for (int n = 0; n < 4; n++) {
        int col_sub = wc * 64 + n * 16 + ccol;
        as4[n] = asrc[head * HID + col_sub];
        ad4[n] = adst[head * HID + col_sub];
    }
#pragma unroll
    for (int m = 0; m < 4; m++)
#pragma unroll
        for (int j = 0; j < 4; j++) {
            float ps = 0.f, pd = 0.f;
#pragma unroll
            for (int n = 0; n < 4; n++) {
                float v = acc[m][n][j];
                ps = fmaf(v, as4[n], ps);
                pd = fmaf(v, ad4[n], pd);
            }
#pragma unroll
            for (int off = 1; off < 16; off <<= 1) {
                ps += __shfl_xor(ps, off);
                pd += __shfl_xor(pd, off);
            }
            if (ccol == 0) {
                int row_sub = wr * 64 + m * 16 + crow + j;
                esP[row_sub][wc] = ps;
                edP[row_sub][wc] = pd;
            }
        }
    __syncthreads();
    if (tid < 128) {
        int r = row0 + tid;
        if (r < Nnodes) {
            es[(size_t)r * 3 + head] = esP[tid][0] + esP[tid][1];
            ed[(size_t)r * 3 + head] = edP[tid][0] + edP[tid][1];
        }
    }
}

// ---------------- per-edge weights ----------------

__global__ void k_edge_w(const int* __restrict__ ssrc, const int* __restrict__ sdst,
                         const float* __restrict__ es, const float* __restrict__ ed,
                         float4* __restrict__ w4, int E) {
    for (int j = blockIdx.x * blockDim.x + threadIdx.x; j < E; j += gridDim.x * blockDim.x) {
        int s = ssrc[j], d = sdst[j];
        float w0 = __expf(lrelu(es[s * 3 + 0] + ed[d * 3 + 0]));
        float w1 = __expf(lrelu(es[s * 3 + 1] + ed[d * 3 + 1]));
        float w2 = __expf(lrelu(es[s * 3 + 2] + ed[d * 3 + 2]));
        w4[j] = make_float4(w0, w1, w2, 0.f);
    }
}

// per-node: self weight + inverse denominators
__global__ void k_den(const float* __restrict__ es, const float* __restrict__ ed,
                      const int* __restrict__ offs, const float4* __restrict__ w4,
                      float4* __restrict__ wself, float4* __restrict__ invden, int Nn) {
    for (int n = blockIdx.x * blockDim.x + threadIdx.x; n < Nn; n += gridDim.x * blockDim.x) {
        float s0 = __expf(lrelu(es[n * 3 + 0] + ed[n * 3 + 0]));
        float s1 = __expf(lrelu(es[n * 3 + 1] + ed[n * 3 + 1]));
        float s2 = __expf(lrelu(es[n * 3 + 2] + ed[n * 3 + 2]));
        float d0 = s0, d1 = s1, d2 = s2;
        int j0 = offs[n], j1 = offs[n + 1];
        int j = j0;
        for (; j + 4 <= j1; j += 4) {
            float4 a = w4[j], b = w4[j + 1], c = w4[j + 2], d = w4[j + 3];
            d0 += a.x + b.x + c.x + d.x;
            d1 += a.y + b.y + c.y + d.y;
            d2 += a.z + b.z + c.z + d.z;
        }
        for (; j < j1; j++) {
            float4 w = w4[j];
            d0 += w.x; d1 += w.y; d2 += w.z;
        }
        wself[n] = make_float4(s0, s1, s2, 0.f);
        invden[n] = make_float4(1.f / d0, 1.f / d1, 1.f / d2, 0.f);
    }
}

// ---------------- wave-per-node aggregation ----------------
// Lane L holds uints {L, L+64, L+128} of the 192-uint H row = channels
// {2L,2L+1} of heads 0,1,2. No LDS, no barriers.

#define EDGE_UNROLL4(body)                                                       \
    int j = j0;                                                                  \
    for (; j + 4 <= j1; j += 4) {                                                \
        int si[4]; float4 wv[4]; unsigned uu[4][3];                              \
        _Pragma("unroll") for (int e = 0; e < 4; e++) si[e] = ssrc[j + e];       \
        _Pragma("unroll") for (int e = 0; e < 4; e++) wv[e] = w4[j + e];         \
        _Pragma("unroll") for (int e = 0; e < 4; e++) {                          \
            const unsigned* rp = Hu + (size_t)si[e] * 192 + L;                   \
            uu[e][0] = rp[0]; uu[e][1] = rp[64]; uu[e][2] = rp[128];             \
        }                                                                        \
        _Pragma("unroll") for (int e = 0; e < 4; e++) { body(wv[e], uu[e]) }     \
    }                                                                            \
    for (; j < j1; j++) {                                                        \
        int s1_ = ssrc[j]; float4 w_ = w4[j];                                    \
        const unsigned* rp = Hu + (size_t)s1_ * 192 + L;                         \
        unsigned u_[3] = {rp[0], rp[64], rp[128]};                               \
        { body(w_, u_) }                                                         \
    }

#define ACC3(wv, uv)                                                             \
    a0[0] = fmaf(wv.x, bflo(uv[0]), a0[0]); a1[0] = fmaf(wv.x, bfhi(uv[0]), a1[0]); \
    a0[1] = fmaf(wv.y, bflo(uv[1]), a0[1]); a1[1] = fmaf(wv.y, bfhi(uv[1]), a1[1]); \
    a0[2] = fmaf(wv.z, bflo(uv[2]), a0[2]); a1[2] = fmaf(wv.z, bfhi(uv[2]), a1[2]);

__global__ __launch_bounds__(256) void k_agg_mean(const unsigned* __restrict__ Hu,
                                                  const float4* __restrict__ w4,
                                                  const float4* __restrict__ wself,
                                                  const float4* __restrict__ invden,
                                                  const int* __restrict__ offs,
                                                  const int* __restrict__ ssrc,
                                                  const float* __restrict__ b,
                                                  unsigned* __restrict__ out, int Nn) {
    int L = threadIdx.x & 63;
    int wstep = gridDim.x * 4;
    for (int n = blockIdx.x * 4 + (threadIdx.x >> 6); n < Nn; n += wstep) {
        float4 ws = wself[n];
        const unsigned* rp = Hu + (size_t)n * 192 + L;
        unsigned u0 = rp[0], u1 = rp[64], u2 = rp[128];
        float a0[3] = {ws.x * bflo(u0), ws.y * bflo(u1), ws.z * bflo(u2)};
        float a1[3] = {ws.x * bfhi(u0), ws.y * bfhi(u1), ws.z * bfhi(u2)};
        int j0 = offs[n], j1 = offs[n + 1];
        EDGE_UNROLL4(ACC3)
        float4 iv = invden[n];
        int c0 = 2 * L;
        float2 bb = *(const float2*)&b[c0];
        float m0 = (a0[0] * iv.x + a0[1] * iv.y + a0[2] * iv.z) * (1.f / 3.f) + bb.x;
        float m1 = (a1[0] * iv.x + a1[1] * iv.y + a1[2] * iv.z) * (1.f / 3.f) + bb.y;
        unsigned short o[2] = {f2bf(rrelu(m0)), f2bf(rrelu(m1))};
        out[(size_t)n * 64 + L] = *(unsigned*)o;
    }
}

__global__ __launch_bounds__(256) void k_agg_cat_final(const unsigned* __restrict__ Hu,
                                                       const float4* __restrict__ w4,
                                                       const float4* __restrict__ wself,
                                                       const float4* __restrict__ invden,
                                                       const int* __restrict__ offs,
                                                       const int* __restrict__ ssrc,
                                                       const float* __restrict__ b,
                                                       const float* __restrict__ Wl,
                                                       const float* __restrict__ bl,
                                                       float* __restrict__ out, int Nn) {
    int L = threadIdx.x & 63;
    int wstep = gridDim.x * 4;
    for (int n = blockIdx.x * 4 + (threadIdx.x >> 6); n < Nn; n += wstep) {
        float4 ws = wself[n];
        const unsigned* rp = Hu + (size_t)n * 192 + L;
        unsigned u0 = rp[0], u1 = rp[64], u2 = rp[128];
        float a0[3] = {ws.x * bflo(u0), ws.y * bflo(u1), ws.z * bflo(u2)};
        float a1[3] = {ws.x * bfhi(u0), ws.y * bfhi(u1), ws.z * bfhi(u2)};
        int j0 = offs[n], j1 = offs[n + 1];
        EDGE_UNROLL4(ACC3)
        float4 iv = invden[n];
        float ivv[3] = {iv.x, iv.y, iv.z};
        float p = 0.f;
#pragma unroll
        for (int k = 0; k < 3; k++) {
            int col = k * HID + 2 * L;
            float2 bb = *(const float2*)&b[col];
            float2 wl = *(const float2*)&Wl[col];
            float r0 = rrelu(a0[k] * ivv[k] + bb.x);
            float r1 = rrelu(a1[k] * ivv[k] + bb.y);
            p = fmaf(r0, wl.x, p);
            p = fmaf(r1, wl.y, p);
        }
#pragma unroll
        for (int off = 32; off > 0; off >>= 1) p += __shfl_down(p, off);
        if (L == 0) out[n] = 1.f / (1.f + __expf(-(p + bl[0])));
    }
}

// ---------------- launch ----------------

extern "C" void kernel_launch(void* const* d_in, const int* in_sizes, int n_in,
                              void* d_out, int out_size, void* d_ws, size_t ws_size,
                              hipStream_t stream) {
    const float* z   = (const float*)d_in[0];
    const float* x   = (const float*)d_in[1];
    const int*   ei  = (const int*)d_in[2];
    const float* W1  = (const float*)d_in[3];
    const float* a1s = (const float*)d_in[4];
    const float* a1d = (const float*)d_in[5];
    const float* b1  = (const float*)d_in[6];
    const float* W2  = (const float*)d_in[7];
    const float* a2s = (const float*)d_in[8];
    const float* a2d = (const float*)d_in[9];
    const float* b2  = (const float*)d_in[10];
    const float* Wl  = (const float*)d_in[11];
    const float* bl  = (const float*)d_in[12];
    float* outp = (float*)d_out;

    int Nn = in_sizes[0] / 128;
    int E  = in_sizes[2] / 2;
    int Mpad = (Nn + 127) & ~127;
    int nb = (Nn + SC_CHUNK - 1) / SC_CHUNK;

    char* p = (char*)d_ws;
    auto carve = [&](size_t bytes) -> char* {
        char* r = p;
        p += (bytes + 255) & ~(size_t)255;
        return r;
    };
    int*            offs   = (int*)carve((size_t)(Nn + 1) * 4);
    int*            cursor = (int*)carve((size_t)Nn * 4);
    int*            ssrc   = (int*)carve((size_t)E * 4);
    int*            sdst   = (int*)carve((size_t)E * 4);
    int*            bsum   = (int*)carve((size_t)(nb + 1) * 4);
    int*            bpre   = (int*)carve((size_t)(nb + 1) * 4);
    float*          e1s    = (float*)carve((size_t)Nn * 3 * 4);
    float*          e1d    = (float*)carve((size_t)Nn * 3 * 4);
    float4*         w4     = (float4*)carve((size_t)E * 16);
    float4*         wself  = (float4*)carve((size_t)Nn * 16);
    float4*         invden = (float4*)carve((size_t)Nn * 16);
    unsigned short* Abf    = (unsigned short*)carve((size_t)Mpad * 256 * 2);
    unsigned short* W1T    = (unsigned short*)carve((size_t)FDIM * 256 * 2);
    unsigned short* W2T    = (unsigned short*)carve((size_t)FDIM * 128 * 2);
    unsigned short* Hbf    = (unsigned short*)carve((size_t)Mpad * FDIM * 2);
    unsigned short* H2in   = (unsigned short*)carve((size_t)Mpad * 128 * 2);

    const int* srcI = ei;
    const int* dstI = ei + E;

    // CSR build
    hipMemsetAsync(cursor, 0, (size_t)Nn * 4, stream);
    k_hist<<<256, 256, 0, stream>>>(dstI, E, cursor);
    k_scan1<<<nb, SC_T, 0, stream>>>(cursor, offs, bsum, Nn);
    k_scan2<<<1, 256, 0, stream>>>(bsum, bpre, nb);
    k_scan3<<<(Nn + 255) / 256, 256, 0, stream>>>(offs, bpre, cursor, Nn, nb);
    k_scatter<<<256, 256, 0, stream>>>(srcI, dstI, E, cursor, ssrc, sdst);

    // bf16 converts
    k_cvt_concat<<<2048, 256, 0, stream>>>(z, x, Abf, Nn, Mpad);
    k_cvt_wt<<<FDIM, 256, 0, stream>>>(W1, W1T, 256, FDIM);
    k_cvt_wt<<<FDIM, 128, 0, stream>>>(W2, W2T, 128, FDIM);
    hipMemsetAsync(H2in + (size_t)Nn * 128, 0, (size_t)(Mpad - Nn) * 128 * 2, stream);

    dim3 gg(Mpad / 128, FDIM / 128);

    // Layer 1 (GEMM + fused logits)
    k_gemm_bf16<<<gg, 256, 0, stream>>>(Abf, W1T, Hbf, 256, FDIM, a1s, a1d, e1s, e1d, Nn);
    k_edge_w<<<1024, 256, 0, stream>>>(ssrc, sdst, e1s, e1d, w4, E);
    k_den<<<(Nn + 255) / 256, 256, 0, stream>>>(e1s, e1d, offs, w4, wself, invden, Nn);
    k_agg_mean<<<2048, 256, 0, stream>>>((const unsigned*)Hbf, w4, wself, invden, offs,
                                         ssrc, b1, (unsigned*)H2in, Nn);

    // Layer 2 (GEMM + fused logits, aggregate + linear + sigmoid)
    k_gemm_bf16<<<gg, 256, 0, stream>>>(H2in, W2T, Hbf, 128, FDIM, a2s, a2d, e1s, e1d, Nn);
    k_edge_w<<<1024, 256, 0, stream>>>(ssrc, sdst, e1s, e1d, w4, E);
    k_den<<<(Nn + 255) / 256, 256, 0, stream>>>(e1s, e1d, offs, w4, wself, invden, Nn);
    k_agg_cat_final<<<2048, 256, 0, stream>>>((const unsigned*)Hbf, w4, wself, invden, offs,
                                              ssrc, b2, Wl, bl, outp, Nn);
}

// Round 8
// 254.714 us; speedup vs baseline: 1.4179x; 1.0469x over previous
//
#include <hip/hip_runtime.h>
#include <stdint.h>

#define HEADS 3
#define HID 128
#define FDIM (HEADS * HID)   // 384

typedef __attribute__((ext_vector_type(8))) short bf16x8;
typedef __attribute__((ext_vector_type(4))) float f32x4;

__device__ __forceinline__ float lrelu(float x) { return x >= 0.f ? x : 0.2f * x; }
__device__ __forceinline__ float rrelu(float x) {
    const float SLOPE = (1.0f / 8.0f + 1.0f / 3.0f) * 0.5f;
    return x >= 0.f ? x : SLOPE * x;
}
__device__ __forceinline__ unsigned short f2bf(float f) {
    union { float f; unsigned u; } c; c.f = f;
    unsigned r = c.u + 0x7FFF + ((c.u >> 16) & 1);   // RNE
    return (unsigned short)(r >> 16);
}
__device__ __forceinline__ float bflo(unsigned u) {
    union { unsigned u; float f; } c; c.u = u << 16; return c.f;
}
__device__ __forceinline__ float bfhi(unsigned u) {
    union { unsigned u; float f; } c; c.u = u & 0xffff0000u; return c.f;
}

__device__ __forceinline__ void gload_lds16(const void* g, void* l) {
    __builtin_amdgcn_global_load_lds(
        (const __attribute__((address_space(1))) void*)g,
        (__attribute__((address_space(3))) void*)l, 16, 0, 0);
}

// ---------------- CSR build (counting sort by dst) ----------------

__global__ void k_hist(const int* __restrict__ dst, int E, int* __restrict__ cnt) {
    for (int i = blockIdx.x * blockDim.x + threadIdx.x; i < E; i += gridDim.x * blockDim.x)
        atomicAdd(&cnt[dst[i]], 1);
}

#define SC_T 256
#define SC_E 8
#define SC_CHUNK (SC_T * SC_E)   // 2048

__global__ __launch_bounds__(SC_T) void k_scan1(const int* __restrict__ cnt,
                                                int* __restrict__ exc,
                                                int* __restrict__ bsum, int n) {
    __shared__ int sm[SC_T];
    int b = blockIdx.x, t = threadIdx.x;
    int base = b * SC_CHUNK + t * SC_E;
    int v[SC_E];
    int s = 0;
#pragma unroll
    for (int i = 0; i < SC_E; i++) {
        int idx = base + i;
        v[i] = (idx < n) ? cnt[idx] : 0;
        s += v[i];
    }
    sm[t] = s;
    __syncthreads();
    for (int off = 1; off < SC_T; off <<= 1) {
        int x = (t >= off) ? sm[t - off] : 0;
        __syncthreads();
        sm[t] += x;
        __syncthreads();
    }
    int run = sm[t] - s;
    if (t == SC_T - 1) bsum[b] = sm[t];
#pragma unroll
    for (int i = 0; i < SC_E; i++) {
        int idx = base + i;
        if (idx < n) exc[idx] = run;
        run += v[i];
    }
}

__global__ __launch_bounds__(256) void k_scan2(const int* __restrict__ bsum,
                                               int* __restrict__ bpre, int nb) {
    __shared__ int sm[256];
    int t = threadIdx.x;
    int v = (t < nb) ? bsum[t] : 0;
    sm[t] = v;
    __syncthreads();
    for (int off = 1; off < 256; off <<= 1) {
        int x = (t >= off) ? sm[t - off] : 0;
        __syncthreads();
        sm[t] += x;
        __syncthreads();
    }
    if (t < nb) bpre[t + 1] = sm[t];
    if (t == 0) bpre[0] = 0;
}

__global__ void k_scan3(int* __restrict__ offs, const int* __restrict__ bpre,
                        int* __restrict__ cursor, int n, int nb) {
    int i = blockIdx.x * blockDim.x + threadIdx.x;
    if (i < n) {
        int o = offs[i] + bpre[i / SC_CHUNK];
        offs[i] = o;
        cursor[i] = o;
    }
    if (i == 0) offs[n] = bpre[nb];
}

__global__ void k_scatter(const int* __restrict__ src, const int* __restrict__ dst, int E,
                          int* __restrict__ cursor, int* __restrict__ ssrc,
                          int* __restrict__ sdst) {
    for (int i = blockIdx.x * blockDim.x + threadIdx.x; i < E; i += gridDim.x * blockDim.x) {
        int d = dst[i];
        int p = atomicAdd(&cursor[d], 1);
        ssrc[p] = src[i];
        sdst[p] = d;
    }
}

// ---------------- bf16 convert (weights only) ----------------

__global__ void k_cvt_wt(const float* __restrict__ W, unsigned short* __restrict__ WT,
                         int K, int Ncols) {
    int n = blockIdx.x;
    for (int k = threadIdx.x; k < K; k += blockDim.x)
        WT[(size_t)n * K + k] = f2bf(W[(size_t)k * Ncols + n]);
}

// ---------------- bf16 MFMA GEMM + fused per-head logits epilogue ----------------
// F32A: A = concat(z,x) fp32, converted in-register during staging.
// else: A = bf16 M x K via global_load_lds.

template <bool F32A>
__global__ __launch_bounds__(256) void k_gemm(
    const void* __restrict__ Ap0, const void* __restrict__ Ap1, int Nn,
    const unsigned short* __restrict__ BT,
    unsigned short* __restrict__ C,
    int K, int Ncols,
    const float* __restrict__ asrc, const float* __restrict__ adst,
    float* __restrict__ es, float* __restrict__ ed, int Nnodes) {
    __shared__ __align__(16) unsigned short As[128 * 32];
    __shared__ __align__(16) unsigned short Bs[128 * 32];
    __shared__ float esP[128][2], edP[128][2];
    int tid = threadIdx.x;
    int w = tid >> 6, lane = tid & 63;
    int row0 = blockIdx.x * 128;
    int col0 = blockIdx.y * 128;
    int wr = w >> 1, wc = w & 1;

    f32x4 acc[4][4] = {};
    int frow = lane & 15;
    int fk = (lane >> 4) * 8;

    for (int k0 = 0; k0 < K; k0 += 32) {
        if (F32A) {
            const float* zf = (const float*)Ap0;
            const float* xf = (const float*)Ap1;
            float4 va[4];
#pragma unroll
            for (int i = 0; i < 4; i++) {
                int idx = i * 256 + tid;          // 0..1023
                int row = idx >> 3;               // 0..127
                int c4 = (idx & 7) * 4;           // 0..28
                int gr = row0 + row;
                const float* sp = (k0 < 128)
                                      ? (zf + (size_t)gr * 128 + k0 + c4)
                                      : (xf + (size_t)gr * 128 + (k0 - 128) + c4);
                va[i] = (gr < Nn) ? *(const float4*)sp
                                  : make_float4(0.f, 0.f, 0.f, 0.f);
            }
            // B staging (async)
#pragma unroll
            for (int i = 0; i < 2; i++) {
                int c = (i * 4 + w) * 64 + lane;
                gload_lds16(BT + (size_t)(col0 + (c >> 2)) * K + k0 + (c & 3) * 8,
                            (char*)Bs + (i * 4 + w) * 1024);
            }
            // convert + LDS write A
#pragma unroll
            for (int i = 0; i < 4; i++) {
                int idx = i * 256 + tid;
                unsigned short o[4] = {f2bf(va[i].x), f2bf(va[i].y),
                                       f2bf(va[i].z), f2bf(va[i].w)};
                *(uint2*)((char*)As + (size_t)idx * 8) = *(uint2*)o;
            }
        } else {
            const unsigned short* A = (const unsigned short*)Ap0;
#pragma unroll
            for (int i = 0; i < 2; i++) {
                int c = (i * 4 + w) * 64 + lane;
                gload_lds16(A + (size_t)(row0 + (c >> 2)) * K + k0 + (c & 3) * 8,
                            (char*)As + (i * 4 + w) * 1024);
            }
#pragma unroll
            for (int i = 0; i < 2; i++) {
                int c = (i * 4 + w) * 64 + lane;
                gload_lds16(BT + (size_t)(col0 + (c >> 2)) * K + k0 + (c & 3) * 8,
                            (char*)Bs + (i * 4 + w) * 1024);
            }
        }
        asm volatile("s_waitcnt vmcnt(0)" ::: "memory");
        __syncthreads();

        bf16x8 af[4], bfr[4];
#pragma unroll
        for (int m = 0; m < 4; m++)
            af[m] = *(const bf16x8*)&As[(wr * 64 + m * 16 + frow) * 32 + fk];
#pragma unroll
        for (int n = 0; n < 4; n++)
            bfr[n] = *(const bf16x8*)&Bs[(wc * 64 + n * 16 + frow) * 32 + fk];
#pragma unroll
        for (int m = 0; m < 4; m++)
#pragma unroll
            for (int n = 0; n < 4; n++)
                acc[m][n] = __builtin_amdgcn_mfma_f32_16x16x32_bf16(af[m], bfr[n], acc[m][n], 0, 0, 0);
        __syncthreads();
    }

    int ccol = lane & 15, crow = (lane >> 4) * 4;

#pragma unroll
    for (int m = 0; m < 4; m++)
#pragma unroll
        for (int n = 0; n < 4; n++)
#pragma unroll
            for (int j = 0; j < 4; j++) {
                int r = row0 + wr * 64 + m * 16 + crow + j;
                int cc = col0 + wc * 64 + n * 16 + ccol;
                C[(size_t)r * Ncols + cc] = f2bf(acc[m][n][j]);
            }

    int head = blockIdx.y;
    float as4[4], ad4[4];
#pragma unroll
    for (int n = 0; n < 4; n++) {
        int col_sub = wc * 64 + n * 16 + ccol;
        as4[n] = asrc[head * HID + col_sub];
        ad4[n] = adst[head * HID + col_sub];
    }
#pragma unroll
    for (int m = 0; m < 4; m++)
#pragma unroll
        for (int j = 0; j < 4; j++) {
            float ps = 0.f, pd = 0.f;
#pragma unroll
            for (int n = 0; n < 4; n++) {
                float v = acc[m][n][j];
                ps = fmaf(v, as4[n], ps);
                pd = fmaf(v, ad4[n], pd);
            }
#pragma unroll
            for (int off = 1; off < 16; off <<= 1) {
                ps += __shfl_xor(ps, off);
                pd += __shfl_xor(pd, off);
            }
            if (ccol == 0) {
                int row_sub = wr * 64 + m * 16 + crow + j;
                esP[row_sub][wc] = ps;
                edP[row_sub][wc] = pd;
            }
        }
    __syncthreads();
    if (tid < 128) {
        int r = row0 + tid;
        if (r < Nnodes) {
            es[(size_t)r * 3 + head] = esP[tid][0] + esP[tid][1];
            ed[(size_t)r * 3 + head] = edP[tid][0] + edP[tid][1];
        }
    }
}

// ---------------- per-edge weights ----------------

__global__ void k_edge_w(const int* __restrict__ ssrc, const int* __restrict__ sdst,
                         const float* __restrict__ es, const float* __restrict__ ed,
                         float4* __restrict__ w4, int E) {
    for (int j = blockIdx.x * blockDim.x + threadIdx.x; j < E; j += gridDim.x * blockDim.x) {
        int s = ssrc[j], d = sdst[j];
        float w0 = __expf(lrelu(es[s * 3 + 0] + ed[d * 3 + 0]));
        float w1 = __expf(lrelu(es[s * 3 + 1] + ed[d * 3 + 1]));
        float w2 = __expf(lrelu(es[s * 3 + 2] + ed[d * 3 + 2]));
        w4[j] = make_float4(w0, w1, w2, 0.f);
    }
}

// ---------------- wave-per-node aggregation (den accumulated inline) ----------------
// Lane L holds uints {L, L+64, L+128} of the 192-uint H row = channels
// {2L,2L+1} of heads 0,1,2. No LDS, no barriers.

#define EDGE_UNROLL4(body)                                                       \
    int j = j0;                                                                  \
    for (; j + 4 <= j1; j += 4) {                                                \
        int si[4]; float4 wv[4]; unsigned uu[4][3];                              \
        _Pragma("unroll") for (int e = 0; e < 4; e++) si[e] = ssrc[j + e];       \
        _Pragma("unroll") for (int e = 0; e < 4; e++) wv[e] = w4[j + e];         \
        _Pragma("unroll") for (int e = 0; e < 4; e++) {                          \
            const unsigned* rp = Hu + (size_t)si[e] * 192 + L;                   \
            uu[e][0] = rp[0]; uu[e][1] = rp[64]; uu[e][2] = rp[128];             \
        }                                                                        \
        _Pragma("unroll") for (int e = 0; e < 4; e++) { body(wv[e], uu[e]) }     \
    }                                                                            \
    for (; j < j1; j++) {                                                        \
        int s1_ = ssrc[j]; float4 w_ = w4[j];                                    \
        const unsigned* rp = Hu + (size_t)s1_ * 192 + L;                         \
        unsigned u_[3] = {rp[0], rp[64], rp[128]};                               \
        { body(w_, u_) }                                                         \
    }

#define ACC3(wv, uv)                                                             \
    a0[0] = fmaf(wv.x, bflo(uv[0]), a0[0]); a1[0] = fmaf(wv.x, bfhi(uv[0]), a1[0]); \
    a0[1] = fmaf(wv.y, bflo(uv[1]), a0[1]); a1[1] = fmaf(wv.y, bfhi(uv[1]), a1[1]); \
    a0[2] = fmaf(wv.z, bflo(uv[2]), a0[2]); a1[2] = fmaf(wv.z, bfhi(uv[2]), a1[2]); \
    den0 += wv.x; den1 += wv.y; den2 += wv.z;

__global__ __launch_bounds__(256) void k_agg_mean(const unsigned* __restrict__ Hu,
                                                  const float4* __restrict__ w4,
                                                  const float* __restrict__ es,
                                                  const float* __restrict__ ed,
                                                  const int* __restrict__ offs,
                                                  const int* __restrict__ ssrc,
                                                  const float* __restrict__ b,
                                                  unsigned* __restrict__ out, int Nn) {
    int L = threadIdx.x & 63;
    int wstep = gridDim.x * 4;
    for (int n = blockIdx.x * 4 + (threadIdx.x >> 6); n < Nn; n += wstep) {
        float s0 = __expf(lrelu(es[n * 3 + 0] + ed[n * 3 + 0]));
        float s1 = __expf(lrelu(es[n * 3 + 1] + ed[n * 3 + 1]));
        float s2 = __expf(lrelu(es[n * 3 + 2] + ed[n * 3 + 2]));
        float den0 = s0, den1 = s1, den2 = s2;
        const unsigned* rp = Hu + (size_t)n * 192 + L;
        unsigned u0 = rp[0], u1 = rp[64], u2 = rp[128];
        float a0[3] = {s0 * bflo(u0), s1 * bflo(u1), s2 * bflo(u2)};
        float a1[3] = {s0 * bfhi(u0), s1 * bfhi(u1), s2 * bfhi(u2)};
        int j0 = offs[n], j1 = offs[n + 1];
        EDGE_UNROLL4(ACC3)
        float iv0 = 1.f / den0, iv1 = 1.f / den1, iv2 = 1.f / den2;
        int c0 = 2 * L;
        float2 bb = *(const float2*)&b[c0];
        float m0 = (a0[0] * iv0 + a0[1] * iv1 + a0[2] * iv2) * (1.f / 3.f) + bb.x;
        float m1 = (a1[0] * iv0 + a1[1] * iv1 + a1[2] * iv2) * (1.f / 3.f) + bb.y;
        unsigned short o[2] = {f2bf(rrelu(m0)), f2bf(rrelu(m1))};
        out[(size_t)n * 64 + L] = *(unsigned*)o;
    }
}

__global__ __launch_bounds__(256) void k_agg_cat_final(const unsigned* __restrict__ Hu,
                                                       const float4* __restrict__ w4,
                                                       const float* __restrict__ es,
                                                       const float* __restrict__ ed,
                                                       const int* __restrict__ offs,
                                                       const int* __restrict__ ssrc,
                                                       const float* __restrict__ b,
                                                       const float* __restrict__ Wl,
                                                       const float* __restrict__ bl,
                                                       float* __restrict__ out, int Nn) {
    int L = threadIdx.x & 63;
    int wstep = gridDim.x * 4;
    for (int n = blockIdx.x * 4 + (threadIdx.x >> 6); n < Nn; n += wstep) {
        float s0 = __expf(lrelu(es[n * 3 + 0] + ed[n * 3 + 0]));
        float s1 = __expf(lrelu(es[n * 3 + 1] + ed[n * 3 + 1]));
        float s2 = __expf(lrelu(es[n * 3 + 2] + ed[n * 3 + 2]));
        float den0 = s0, den1 = s1, den2 = s2;
        const unsigned* rp = Hu + (size_t)n * 192 + L;
        unsigned u0 = rp[0], u1 = rp[64], u2 = rp[128];
        float a0[3] = {s0 * bflo(u0), s1 * bflo(u1), s2 * bflo(u2)};
        float a1[3] = {s0 * bfhi(u0), s1 * bfhi(u1), s2 * bfhi(u2)};
        int j0 = offs[n], j1 = offs[n + 1];
        EDGE_UNROLL4(ACC3)
        float ivv[3] = {1.f / den0, 1.f / den1, 1.f / den2};
        float p = 0.f;
#pragma unroll
        for (int k = 0; k < 3; k++) {
            int col = k * HID + 2 * L;
            float2 bb = *(const float2*)&b[col];
            float2 wl = *(const float2*)&Wl[col];
            float r0 = rrelu(a0[k] * ivv[k] + bb.x);
            float r1 = rrelu(a1[k] * ivv[k] + bb.y);
            p = fmaf(r0, wl.x, p);
            p = fmaf(r1, wl.y, p);
        }
#pragma unroll
        for (int off = 32; off > 0; off >>= 1) p += __shfl_down(p, off);
        if (L == 0) out[n] = 1.f / (1.f + __expf(-(p + bl[0])));
    }
}

// ---------------- launch ----------------

extern "C" void kernel_launch(void* const* d_in, const int* in_sizes, int n_in,
                              void* d_out, int out_size, void* d_ws, size_t ws_size,
                              hipStream_t stream) {
    const float* z   = (const float*)d_in[0];
    const float* x   = (const float*)d_in[1];
    const int*   ei  = (const int*)d_in[2];
    const float* W1  = (const float*)d_in[3];
    const float* a1s = (const float*)d_in[4];
    const float* a1d = (const float*)d_in[5];
    const float* b1  = (const float*)d_in[6];
    const float* W2  = (const float*)d_in[7];
    const float* a2s = (const float*)d_in[8];
    const float* a2d = (const float*)d_in[9];
    const float* b2  = (const float*)d_in[10];
    const float* Wl  = (const float*)d_in[11];
    const float* bl  = (const float*)d_in[12];
    float* outp = (float*)d_out;

    int Nn = in_sizes[0] / 128;
    int E  = in_sizes[2] / 2;
    int Mpad = (Nn + 127) & ~127;
    int nb = (Nn + SC_CHUNK - 1) / SC_CHUNK;

    char* p = (char*)d_ws;
    auto carve = [&](size_t bytes) -> char* {
        char* r = p;
        p += (bytes + 255) & ~(size_t)255;
        return r;
    };
    int*            offs   = (int*)carve((size_t)(Nn + 1) * 4);
    int*            cursor = (int*)carve((size_t)Nn * 4);
    int*            ssrc   = (int*)carve((size_t)E * 4);
    int*            sdst   = (int*)carve((size_t)E * 4);
    int*            bsum   = (int*)carve((size_t)(nb + 1) * 4);
    int*            bpre   = (int*)carve((size_t)(nb + 1) * 4);
    float*          e1s    = (float*)carve((size_t)Nn * 3 * 4);
    float*          e1d    = (float*)carve((size_t)Nn * 3 * 4);
    float4*         w4     = (float4*)carve((size_t)E * 16);
    unsigned short* W1T    = (unsigned short*)carve((size_t)FDIM * 256 * 2);
    unsigned short* W2T    = (unsigned short*)carve((size_t)FDIM * 128 * 2);
    unsigned short* Hbf    = (unsigned short*)carve((size_t)Mpad * FDIM * 2);
    unsigned short* H2in   = (unsigned short*)carve((size_t)Mpad * 128 * 2);

    const int* srcI = ei;
    const int* dstI = ei + E;

    // CSR build
    hipMemsetAsync(cursor, 0, (size_t)Nn * 4, stream);
    k_hist<<<1024, 256, 0, stream>>>(dstI, E, cursor);
    k_scan1<<<nb, SC_T, 0, stream>>>(cursor, offs, bsum, Nn);
    k_scan2<<<1, 256, 0, stream>>>(bsum, bpre, nb);
    k_scan3<<<(Nn + 255) / 256, 256, 0, stream>>>(offs, bpre, cursor, Nn, nb);
    k_scatter<<<1024, 256, 0, stream>>>(srcI, dstI, E, cursor, ssrc, sdst);

    // weight converts
    k_cvt_wt<<<FDIM, 256, 0, stream>>>(W1, W1T, 256, FDIM);
    k_cvt_wt<<<FDIM, 128, 0, stream>>>(W2, W2T, 128, FDIM);
    hipMemsetAsync(H2in + (size_t)Nn * 128, 0, (size_t)(Mpad - Nn) * 128 * 2, stream);

    dim3 gg(Mpad / 128, FDIM / 128);

    // Layer 1 (fp32-A GEMM + fused logits)
    k_gemm<true><<<gg, 256, 0, stream>>>(z, x, Nn, W1T, Hbf, 256, FDIM,
                                         a1s, a1d, e1s, e1d, Nn);
    k_edge_w<<<1024, 256, 0, stream>>>(ssrc, sdst, e1s, e1d, w4, E);
    k_agg_mean<<<2048, 256, 0, stream>>>((const unsigned*)Hbf, w4, e1s, e1d, offs,
                                         ssrc, b1, (unsigned*)H2in, Nn);

    // Layer 2 (bf16 GEMM + fused logits, aggregate + linear + sigmoid)
    k_gemm<false><<<gg, 256, 0, stream>>>(H2in, nullptr, Mpad, W2T, Hbf, 128, FDIM,
                                          a2s, a2d, e1s, e1d, Nn);
    k_edge_w<<<1024, 256, 0, stream>>>(ssrc, sdst, e1s, e1d, w4, E);
    k_agg_cat_final<<<2048, 256, 0, stream>>>((const unsigned*)Hbf, w4, e1s, e1d, offs,
                                              ssrc, b2, Wl, bl, outp, Nn);
}

// Round 9
// 248.454 us; speedup vs baseline: 1.4536x; 1.0252x over previous
//
#include <hip/hip_runtime.h>
#include <stdint.h>

#define HEADS 3
#define HID 128
#define FDIM (HEADS * HID)   // 384

typedef __attribute__((ext_vector_type(8))) short bf16x8;
typedef __attribute__((ext_vector_type(4))) float f32x4;

__device__ __forceinline__ float lrelu(float x) { return x >= 0.f ? x : 0.2f * x; }
__device__ __forceinline__ float rrelu(float x) {
    const float SLOPE = (1.0f / 8.0f + 1.0f / 3.0f) * 0.5f;
    return x >= 0.f ? x : SLOPE * x;
}
__device__ __forceinline__ unsigned short f2bf(float f) {
    union { float f; unsigned u; } c; c.f = f;
    unsigned r = c.u + 0x7FFF + ((c.u >> 16) & 1);   // RNE
    return (unsigned short)(r >> 16);
}
__device__ __forceinline__ float bflo(unsigned u) {
    union { unsigned u; float f; } c; c.u = u << 16; return c.f;
}
__device__ __forceinline__ float bfhi(unsigned u) {
    union { unsigned u; float f; } c; c.u = u & 0xffff0000u; return c.f;
}

__device__ __forceinline__ void gload_lds16(const void* g, void* l) {
    __builtin_amdgcn_global_load_lds(
        (const __attribute__((address_space(1))) void*)g,
        (__attribute__((address_space(3))) void*)l, 16, 0, 0);
}

// ---------------- CSR build (counting sort by dst) ----------------

__global__ void k_hist(const int* __restrict__ dst, int E, int* __restrict__ cnt) {
    for (int i = blockIdx.x * blockDim.x + threadIdx.x; i < E; i += gridDim.x * blockDim.x)
        atomicAdd(&cnt[dst[i]], 1);
}

#define SC_T 256
#define SC_E 8
#define SC_CHUNK (SC_T * SC_E)   // 2048

__global__ __launch_bounds__(SC_T) void k_scan1(const int* __restrict__ cnt,
                                                int* __restrict__ exc,
                                                int* __restrict__ bsum, int n) {
    __shared__ int sm[SC_T];
    int b = blockIdx.x, t = threadIdx.x;
    int base = b * SC_CHUNK + t * SC_E;
    int v[SC_E];
    int s = 0;
#pragma unroll
    for (int i = 0; i < SC_E; i++) {
        int idx = base + i;
        v[i] = (idx < n) ? cnt[idx] : 0;
        s += v[i];
    }
    sm[t] = s;
    __syncthreads();
    for (int off = 1; off < SC_T; off <<= 1) {
        int x = (t >= off) ? sm[t - off] : 0;
        __syncthreads();
        sm[t] += x;
        __syncthreads();
    }
    int run = sm[t] - s;
    if (t == SC_T - 1) bsum[b] = sm[t];
#pragma unroll
    for (int i = 0; i < SC_E; i++) {
        int idx = base + i;
        if (idx < n) exc[idx] = run;
        run += v[i];
    }
}

__global__ __launch_bounds__(256) void k_scan2(const int* __restrict__ bsum,
                                               int* __restrict__ bpre, int nb) {
    __shared__ int sm[256];
    int t = threadIdx.x;
    int v = (t < nb) ? bsum[t] : 0;
    sm[t] = v;
    __syncthreads();
    for (int off = 1; off < 256; off <<= 1) {
        int x = (t >= off) ? sm[t - off] : 0;
        __syncthreads();
        sm[t] += x;
        __syncthreads();
    }
    if (t < nb) bpre[t + 1] = sm[t];
    if (t == 0) bpre[0] = 0;
}

__global__ void k_scan3(int* __restrict__ offs, const int* __restrict__ bpre,
                        int* __restrict__ cursor, int n, int nb) {
    int i = blockIdx.x * blockDim.x + threadIdx.x;
    if (i < n) {
        int o = offs[i] + bpre[i / SC_CHUNK];
        offs[i] = o;
        cursor[i] = o;
    }
    if (i == 0) offs[n] = bpre[nb];
}

__global__ void k_scatter(const int* __restrict__ src, const int* __restrict__ dst, int E,
                          int* __restrict__ cursor, int* __restrict__ ssrc,
                          int* __restrict__ sdst) {
    for (int i = blockIdx.x * blockDim.x + threadIdx.x; i < E; i += gridDim.x * blockDim.x) {
        int d = dst[i];
        int p = atomicAdd(&cursor[d], 1);
        ssrc[p] = src[i];
        sdst[p] = d;
    }
}

// ---------------- bf16 convert (weights only) ----------------

__global__ void k_cvt_wt(const float* __restrict__ W, unsigned short* __restrict__ WT,
                         int K, int Ncols) {
    int n = blockIdx.x;
    for (int k = threadIdx.x; k < K; k += blockDim.x)
        WT[(size_t)n * K + k] = f2bf(W[(size_t)k * Ncols + n]);
}

// ---------------- bf16 MFMA GEMM (64x128 tile) + fused logits epilogue ----------------
// F32A: A = concat(z,x) fp32, converted in-register, va prefetched one tile ahead.
// else: A = bf16 via global_load_lds.

template <bool F32A>
__global__ __launch_bounds__(256) void k_gemm(
    const void* __restrict__ Ap0, const void* __restrict__ Ap1, int Nn,
    const unsigned short* __restrict__ BT,
    unsigned short* __restrict__ C,
    int K, int Ncols,
    const float* __restrict__ asrc, const float* __restrict__ adst,
    float* __restrict__ es, float* __restrict__ ed, int Nnodes) {
    __shared__ __align__(16) unsigned short As[64 * 32];
    __shared__ __align__(16) unsigned short Bs[128 * 32];
    __shared__ float esP[64][2], edP[64][2];
    int tid = threadIdx.x;
    int w = tid >> 6, lane = tid & 63;
    int row0 = blockIdx.x * 64;
    int head = blockIdx.y;
    int col0 = head * 128;
    int wr = w >> 1, wc = w & 1;     // wave: rows wr*32..+32, cols wc*64..+64

    f32x4 acc[2][4] = {};
    int frow = lane & 15;
    int fk = (lane >> 4) * 8;

    const float* zf = (const float*)Ap0;
    const float* xf = (const float*)Ap1;
    float4 va[2];
    if (F32A) {
#pragma unroll
        for (int i = 0; i < 2; i++) {
            int idx = i * 256 + tid;
            int row = idx >> 3, c4 = (idx & 7) * 4;
            int gr = row0 + row;
            const float* sp = zf + (size_t)gr * 128 + c4;      // k0 = 0
            va[i] = (gr < Nn) ? *(const float4*)sp : make_float4(0.f, 0.f, 0.f, 0.f);
        }
    }

    for (int k0 = 0; k0 < K; k0 += 32) {
        // stage B (async)
#pragma unroll
        for (int i = 0; i < 2; i++) {
            int c = (i * 4 + w) * 64 + lane;
            gload_lds16(BT + (size_t)(col0 + (c >> 2)) * K + k0 + (c & 3) * 8,
                        (char*)Bs + (i * 4 + w) * 1024);
        }
        if (F32A) {
            // convert + LDS write A (waits on va loads)
#pragma unroll
            for (int i = 0; i < 2; i++) {
                int idx = i * 256 + tid;
                unsigned short o[4] = {f2bf(va[i].x), f2bf(va[i].y),
                                       f2bf(va[i].z), f2bf(va[i].w)};
                *(uint2*)((char*)As + (size_t)idx * 8) = *(uint2*)o;
            }
        } else {
            const unsigned short* A = (const unsigned short*)Ap0;
            int c = tid;
            gload_lds16(A + (size_t)(row0 + (c >> 2)) * K + k0 + (c & 3) * 8,
                        (char*)As + w * 1024);
        }
        asm volatile("s_waitcnt vmcnt(0)" ::: "memory");
        __syncthreads();

        // prefetch next A tile (stays in flight through MFMA; waited at next As write)
        if (F32A && (k0 + 32 < K)) {
            int kn = k0 + 32;
#pragma unroll
            for (int i = 0; i < 2; i++) {
                int idx = i * 256 + tid;
                int row = idx >> 3, c4 = (idx & 7) * 4;
                int gr = row0 + row;
                const float* sp = (kn < 128)
                                      ? (zf + (size_t)gr * 128 + kn + c4)
                                      : (xf + (size_t)gr * 128 + (kn - 128) + c4);
                va[i] = (gr < Nn) ? *(const float4*)sp : make_float4(0.f, 0.f, 0.f, 0.f);
            }
        }

        bf16x8 af[2], bfr[4];
#pragma unroll
        for (int m = 0; m < 2; m++)
            af[m] = *(const bf16x8*)&As[(wr * 32 + m * 16 + frow) * 32 + fk];
#pragma unroll
        for (int n = 0; n < 4; n++)
            bfr[n] = *(const bf16x8*)&Bs[(wc * 64 + n * 16 + frow) * 32 + fk];
#pragma unroll
        for (int m = 0; m < 2; m++)
#pragma unroll
            for (int n = 0; n < 4; n++)
                acc[m][n] = __builtin_amdgcn_mfma_f32_16x16x32_bf16(af[m], bfr[n], acc[m][n], 0, 0, 0);
        __syncthreads();
    }

    int ccol = lane & 15, crow = (lane >> 4) * 4;

    // C write
#pragma unroll
    for (int m = 0; m < 2; m++)
#pragma unroll
        for (int n = 0; n < 4; n++)
#pragma unroll
            for (int j = 0; j < 4; j++) {
                int r = row0 + wr * 32 + m * 16 + crow + j;
                int cc = col0 + wc * 64 + n * 16 + ccol;
                C[(size_t)r * Ncols + cc] = f2bf(acc[m][n][j]);
            }

    // fused logits
    float as4[4], ad4[4];
#pragma unroll
    for (int n = 0; n < 4; n++) {
        int col_sub = wc * 64 + n * 16 + ccol;
        as4[n] = asrc[head * HID + col_sub];
        ad4[n] = adst[head * HID + col_sub];
    }
#pragma unroll
    for (int m = 0; m < 2; m++)
#pragma unroll
        for (int j = 0; j < 4; j++) {
            float ps = 0.f, pd = 0.f;
#pragma unroll
            for (int n = 0; n < 4; n++) {
                float v = acc[m][n][j];
                ps = fmaf(v, as4[n], ps);
                pd = fmaf(v, ad4[n], pd);
            }
#pragma unroll
            for (int off = 1; off < 16; off <<= 1) {
                ps += __shfl_xor(ps, off);
                pd += __shfl_xor(pd, off);
            }
            if (ccol == 0) {
                int row_sub = wr * 32 + m * 16 + crow + j;
                esP[row_sub][wc] = ps;
                edP[row_sub][wc] = pd;
            }
        }
    __syncthreads();
    if (tid < 64) {
        int r = row0 + tid;
        if (r < Nnodes) {
            es[(size_t)r * 3 + head] = esP[tid][0] + esP[tid][1];
            ed[(size_t)r * 3 + head] = edP[tid][0] + edP[tid][1];
        }
    }
}

// ---------------- per-edge weights ----------------

__global__ void k_edge_w(const int* __restrict__ ssrc, const int* __restrict__ sdst,
                         const float* __restrict__ es, const float* __restrict__ ed,
                         float4* __restrict__ w4, int E) {
    for (int j = blockIdx.x * blockDim.x + threadIdx.x; j < E; j += gridDim.x * blockDim.x) {
        int s = ssrc[j], d = sdst[j];
        float w0 = __expf(lrelu(es[s * 3 + 0] + ed[d * 3 + 0]));
        float w1 = __expf(lrelu(es[s * 3 + 1] + ed[d * 3 + 1]));
        float w2 = __expf(lrelu(es[s * 3 + 2] + ed[d * 3 + 2]));
        w4[j] = make_float4(w0, w1, w2, 0.f);
    }
}

// ---------------- wave-per-node aggregation (den accumulated inline) ----------------

#define EDGE_UNROLL4(body)                                                       \
    int j = j0;                                                                  \
    for (; j + 4 <= j1; j += 4) {                                                \
        int si[4]; float4 wv[4]; unsigned uu[4][3];                              \
        _Pragma("unroll") for (int e = 0; e < 4; e++) si[e] = ssrc[j + e];       \
        _Pragma("unroll") for (int e = 0; e < 4; e++) wv[e] = w4[j + e];         \
        _Pragma("unroll") for (int e = 0; e < 4; e++) {                          \
            const unsigned* rp = Hu + (size_t)si[e] * 192 + L;                   \
            uu[e][0] = rp[0]; uu[e][1] = rp[64]; uu[e][2] = rp[128];             \
        }                                                                        \
        _Pragma("unroll") for (int e = 0; e < 4; e++) { body(wv[e], uu[e]) }     \
    }                                                                            \
    for (; j < j1; j++) {                                                        \
        int s1_ = ssrc[j]; float4 w_ = w4[j];                                    \
        const unsigned* rp = Hu + (size_t)s1_ * 192 + L;                         \
        unsigned u_[3] = {rp[0], rp[64], rp[128]};                               \
        { body(w_, u_) }                                                         \
    }

#define ACC3(wv, uv)                                                             \
    a0[0] = fmaf(wv.x, bflo(uv[0]), a0[0]); a1[0] = fmaf(wv.x, bfhi(uv[0]), a1[0]); \
    a0[1] = fmaf(wv.y, bflo(uv[1]), a0[1]); a1[1] = fmaf(wv.y, bfhi(uv[1]), a1[1]); \
    a0[2] = fmaf(wv.z, bflo(uv[2]), a0[2]); a1[2] = fmaf(wv.z, bfhi(uv[2]), a1[2]); \
    den0 += wv.x; den1 += wv.y; den2 += wv.z;

__global__ __launch_bounds__(256) void k_agg_mean(const unsigned* __restrict__ Hu,
                                                  const float4* __restrict__ w4,
                                                  const float* __restrict__ es,
                                                  const float* __restrict__ ed,
                                                  const int* __restrict__ offs,
                                                  const int* __restrict__ ssrc,
                                                  const float* __restrict__ b,
                                                  unsigned* __restrict__ out, int Nn) {
    int L = threadIdx.x & 63;
    int wstep = gridDim.x * 4;
    for (int n = blockIdx.x * 4 + (threadIdx.x >> 6); n < Nn; n += wstep) {
        float s0 = __expf(lrelu(es[n * 3 + 0] + ed[n * 3 + 0]));
        float s1 = __expf(lrelu(es[n * 3 + 1] + ed[n * 3 + 1]));
        float s2 = __expf(lrelu(es[n * 3 + 2] + ed[n * 3 + 2]));
        float den0 = s0, den1 = s1, den2 = s2;
        const unsigned* rp = Hu + (size_t)n * 192 + L;
        unsigned u0 = rp[0], u1 = rp[64], u2 = rp[128];
        float a0[3] = {s0 * bflo(u0), s1 * bflo(u1), s2 * bflo(u2)};
        float a1[3] = {s0 * bfhi(u0), s1 * bfhi(u1), s2 * bfhi(u2)};
        int j0 = offs[n], j1 = offs[n + 1];
        EDGE_UNROLL4(ACC3)
        float iv0 = 1.f / den0, iv1 = 1.f / den1, iv2 = 1.f / den2;
        int c0 = 2 * L;
        float2 bb = *(const float2*)&b[c0];
        float m0 = (a0[0] * iv0 + a0[1] * iv1 + a0[2] * iv2) * (1.f / 3.f) + bb.x;
        float m1 = (a1[0] * iv0 + a1[1] * iv1 + a1[2] * iv2) * (1.f / 3.f) + bb.y;
        unsigned short o[2] = {f2bf(rrelu(m0)), f2bf(rrelu(m1))};
        out[(size_t)n * 64 + L] = *(unsigned*)o;
    }
}

__global__ __launch_bounds__(256) void k_agg_cat_final(const unsigned* __restrict__ Hu,
                                                       const float4* __restrict__ w4,
                                                       const float* __restrict__ es,
                                                       const float* __restrict__ ed,
                                                       const int* __restrict__ offs,
                                                       const int* __restrict__ ssrc,
                                                       const float* __restrict__ b,
                                                       const float* __restrict__ Wl,
                                                       const float* __restrict__ bl,
                                                       float* __restrict__ out, int Nn) {
    int L = threadIdx.x & 63;
    int wstep = gridDim.x * 4;
    for (int n = blockIdx.x * 4 + (threadIdx.x >> 6); n < Nn; n += wstep) {
        float s0 = __expf(lrelu(es[n * 3 + 0] + ed[n * 3 + 0]));
        float s1 = __expf(lrelu(es[n * 3 + 1] + ed[n * 3 + 1]));
        float s2 = __expf(lrelu(es[n * 3 + 2] + ed[n * 3 + 2]));
        float den0 = s0, den1 = s1, den2 = s2;
        const unsigned* rp = Hu + (size_t)n * 192 + L;
        unsigned u0 = rp[0], u1 = rp[64], u2 = rp[128];
        float a0[3] = {s0 * bflo(u0), s1 * bflo(u1), s2 * bflo(u2)};
        float a1[3] = {s0 * bfhi(u0), s1 * bfhi(u1), s2 * bfhi(u2)};
        int j0 = offs[n], j1 = offs[n + 1];
        EDGE_UNROLL4(ACC3)
        float ivv[3] = {1.f / den0, 1.f / den1, 1.f / den2};
        float p = 0.f;
#pragma unroll
        for (int k = 0; k < 3; k++) {
            int col = k * HID + 2 * L;
            float2 bb = *(const float2*)&b[col];
            float2 wl = *(const float2*)&Wl[col];
            float r0 = rrelu(a0[k] * ivv[k] + bb.x);
            float r1 = rrelu(a1[k] * ivv[k] + bb.y);
            p = fmaf(r0, wl.x, p);
            p = fmaf(r1, wl.y, p);
        }
#pragma unroll
        for (int off = 32; off > 0; off >>= 1) p += __shfl_down(p, off);
        if (L == 0) out[n] = 1.f / (1.f + __expf(-(p + bl[0])));
    }
}

// ---------------- launch ----------------

extern "C" void kernel_launch(void* const* d_in, const int* in_sizes, int n_in,
                              void* d_out, int out_size, void* d_ws, size_t ws_size,
                              hipStream_t stream) {
    const float* z   = (const float*)d_in[0];
    const float* x   = (const float*)d_in[1];
    const int*   ei  = (const int*)d_in[2];
    const float* W1  = (const float*)d_in[3];
    const float* a1s = (const float*)d_in[4];
    const float* a1d = (const float*)d_in[5];
    const float* b1  = (const float*)d_in[6];
    const float* W2  = (const float*)d_in[7];
    const float* a2s = (const float*)d_in[8];
    const float* a2d = (const float*)d_in[9];
    const float* b2  = (const float*)d_in[10];
    const float* Wl  = (const float*)d_in[11];
    const float* bl  = (const float*)d_in[12];
    float* outp = (float*)d_out;

    int Nn = in_sizes[0] / 128;
    int E  = in_sizes[2] / 2;
    int Mpad = (Nn + 127) & ~127;
    int nb = (Nn + SC_CHUNK - 1) / SC_CHUNK;

    char* p = (char*)d_ws;
    auto carve = [&](size_t bytes) -> char* {
        char* r = p;
        p += (bytes + 255) & ~(size_t)255;
        return r;
    };
    int*            offs   = (int*)carve((size_t)(Nn + 1) * 4);
    int*            cursor = (int*)carve((size_t)Nn * 4);
    int*            ssrc   = (int*)carve((size_t)E * 4);
    int*            sdst   = (int*)carve((size_t)E * 4);
    int*            bsum   = (int*)carve((size_t)(nb + 1) * 4);
    int*            bpre   = (int*)carve((size_t)(nb + 1) * 4);
    float*          e1s    = (float*)carve((size_t)Nn * 3 * 4);
    float*          e1d    = (float*)carve((size_t)Nn * 3 * 4);
    float4*         w4     = (float4*)carve((size_t)E * 16);
    unsigned short* W1T    = (unsigned short*)carve((size_t)FDIM * 256 * 2);
    unsigned short* W2T    = (unsigned short*)carve((size_t)FDIM * 128 * 2);
    unsigned short* Hbf    = (unsigned short*)carve((size_t)Mpad * FDIM * 2);
    unsigned short* H2in   = (unsigned short*)carve((size_t)Mpad * 128 * 2);

    const int* srcI = ei;
    const int* dstI = ei + E;

    // CSR build
    hipMemsetAsync(cursor, 0, (size_t)Nn * 4, stream);
    k_hist<<<1024, 256, 0, stream>>>(dstI, E, cursor);
    k_scan1<<<nb, SC_T, 0, stream>>>(cursor, offs, bsum, Nn);
    k_scan2<<<1, 256, 0, stream>>>(bsum, bpre, nb);
    k_scan3<<<(Nn + 255) / 256, 256, 0, stream>>>(offs, bpre, cursor, Nn, nb);
    k_scatter<<<1024, 256, 0, stream>>>(srcI, dstI, E, cursor, ssrc, sdst);

    // weight converts
    k_cvt_wt<<<FDIM, 256, 0, stream>>>(W1, W1T, 256, FDIM);
    k_cvt_wt<<<FDIM, 128, 0, stream>>>(W2, W2T, 128, FDIM);
    hipMemsetAsync(H2in + (size_t)Nn * 128, 0, (size_t)(Mpad - Nn) * 128 * 2, stream);

    dim3 gg(Mpad / 64, FDIM / 128);

    // Layer 1 (fp32-A GEMM + fused logits)
    k_gemm<true><<<gg, 256, 0, stream>>>(z, x, Nn, W1T, Hbf, 256, FDIM,
                                         a1s, a1d, e1s, e1d, Nn);
    k_edge_w<<<1024, 256, 0, stream>>>(ssrc, sdst, e1s, e1d, w4, E);
    k_agg_mean<<<2048, 256, 0, stream>>>((const unsigned*)Hbf, w4, e1s, e1d, offs,
                                         ssrc, b1, (unsigned*)H2in, Nn);

    // Layer 2 (bf16 GEMM + fused logits, aggregate + linear + sigmoid)
    k_gemm<false><<<gg, 256, 0, stream>>>(H2in, nullptr, Mpad, W2T, Hbf, 128, FDIM,
                                          a2s, a2d, e1s, e1d, Nn);
    k_edge_w<<<1024, 256, 0, stream>>>(ssrc, sdst, e1s, e1d, w4, E);
    k_agg_cat_final<<<2048, 256, 0, stream>>>((const unsigned*)Hbf, w4, e1s, e1d, offs,
                                              ssrc, b2, Wl, bl, outp, Nn);
}